// Round 1
// baseline (428.446 us; speedup 1.0000x reference)
//
#include <hip/hip_runtime.h>

typedef unsigned short u16;
typedef u16 u16x4 __attribute__((ext_vector_type(4)));
typedef u16 u16x8 __attribute__((ext_vector_type(8)));
typedef __bf16 bf16x8 __attribute__((ext_vector_type(8)));
typedef float f32x4 __attribute__((ext_vector_type(4)));

#define DEVI __device__ __forceinline__

#if __has_builtin(__builtin_amdgcn_exp2f)
#define EXP2F __builtin_amdgcn_exp2f
#else
#define EXP2F exp2f
#endif

// ---------- helpers ----------
DEVI u16 f2b(float f) {  // fp32 -> bf16 RNE
  unsigned u = __builtin_bit_cast(unsigned, f);
  u += 0x7fffu + ((u >> 16) & 1u);
  return (u16)(u >> 16);
}

DEVI float b2f(u16 v) { return __builtin_bit_cast(float, (unsigned)v << 16); }

DEVI f32x4 mfma16(u16x8 a, u16x8 b, f32x4 c) {
  return __builtin_amdgcn_mfma_f32_16x16x32_bf16(
      __builtin_bit_cast(bf16x8, a), __builtin_bit_cast(bf16x8, b), c, 0, 0, 0);
}

DEVI void async_copy16(const u16* g, u16* l) {
  __builtin_amdgcn_global_load_lds(
      (__attribute__((address_space(1))) unsigned int*)(g),
      (__attribute__((address_space(3))) unsigned int*)(l), 16, 0, 0);
}

// ---------- 1. hs->bf16 + gate ----------
__global__ void prep_kernel(const float* __restrict__ hs, const float* __restrict__ mask,
                            const float* __restrict__ ww, const float* __restrict__ wb,
                            u16* __restrict__ hsb, float* __restrict__ wgate) {
  int token = blockIdx.x;            // 0..4095
  int tid = threadIdx.x;             // 256
  const float* row = hs + (size_t)token * 1280;
  u16* orow = hsb + (size_t)token * 1280;
  float acc = 0.f;
#pragma unroll
  for (int i = 0; i < 5; i++) {
    int c = i * 256 + tid;
    float v = row[c];
    orow[c] = f2b(v);
    acc += v * ww[c];
  }
#pragma unroll
  for (int off = 1; off < 64; off <<= 1) acc += __shfl_xor(acc, off);
  __shared__ float partial[4];
  int wid = tid >> 6;
  if ((tid & 63) == 0) partial[wid] = acc;
  __syncthreads();
  if (tid == 0) {
    float tot = partial[0] + partial[1] + partial[2] + partial[3];
    int b = token >> 11, t = token & 2047;
    int s = t & 1023;
    float mv = mask[b * 65536 + ((s >> 5) * 8) * 256 + (s & 31) * 8];
    float z = tot + mv * ww[1280] + wb[0];
    wgate[token] = 1.f / (1.f + __expf(-z));
  }
}

// ---------- 2. weight transpose + bf16 ----------
__global__ void wtrans_kernel(const float* w0, const float* w1, const float* w2,
                              const float* w3, const float* w4, const float* w5,
                              const float* w6, u16* __restrict__ out) {
  const float* src;
  switch (blockIdx.z) {
    case 0: src = w0; break; case 1: src = w1; break; case 2: src = w2; break;
    case 3: src = w3; break; case 4: src = w4; break; case 5: src = w5; break;
    default: src = w6; break;
  }
  u16* dst = out + (size_t)blockIdx.z * 1280 * 1280;
  __shared__ float tile[32][33];
  int tx = threadIdx.x & 31, ty = threadIdx.x >> 5;   // 32x8
  int k0 = blockIdx.x * 32, n0 = blockIdx.y * 32;
#pragma unroll
  for (int r = 0; r < 4; r++)
    tile[ty + r * 8][tx] = src[(size_t)(k0 + ty + r * 8) * 1280 + n0 + tx];
  __syncthreads();
#pragma unroll
  for (int r = 0; r < 4; r++)
    dst[(size_t)(n0 + ty + r * 8) * 1280 + k0 + tx] = f2b(tile[tx][ty + r * 8]);
}

// ---------- 3. merged QKV GEMM: 4 uniform 128x128 tile jobs per (nb,mb) ----------
// z=0: A@attn_wq -> Qa ; z=1: A@proc_wq -> Qp ; z=2: K (half-selected) -> Kb row-major
// z=3: V (half-selected) -> VTb transposed [b*8+h][160][2048]
__launch_bounds__(256)
__global__ void gemm_qkv_kernel(const u16* __restrict__ A, const u16* __restrict__ Wt,
                                u16* __restrict__ Qa, u16* __restrict__ Qp,
                                u16* __restrict__ Kout, u16* __restrict__ VTout) {
  const int K = 1280, N = 1280;
  const size_t WSZ = (size_t)1280 * 1280;
  __shared__ u16 As[128 * 32];
  __shared__ u16 Bs[128 * 32];

  int tid = threadIdx.x;
  int wid = tid >> 6, lane = tid & 63;
  int nb = blockIdx.x, mb = blockIdx.y, z = blockIdx.z;
  int m0 = mb * 128, n0 = nb * 128;
  bool first = ((m0 & 2047) < 1024);   // first half of sequence -> attn weights

  const u16* B;
  switch (z) {
    case 0:  B = Wt + 0 * WSZ; break;
    case 1:  B = Wt + 4 * WSZ; break;
    case 2:  B = first ? Wt + 1 * WSZ : Wt + 5 * WSZ; break;
    default: B = first ? Wt + 2 * WSZ : Wt + 6 * WSZ; break;
  }

  f32x4 zero = {0.f, 0.f, 0.f, 0.f};
  f32x4 acc[4][4];
#pragma unroll
  for (int i = 0; i < 4; i++)
#pragma unroll
    for (int j = 0; j < 4; j++) acc[i][j] = zero;

  int wr = wid >> 1, wc = wid & 1;

  for (int kk = 0; kk < 40; kk++) {
    int k0 = kk * 32;
#pragma unroll
    for (int i = 0; i < 2; i++) {
      int slot = i * 256 + tid;
      int row = slot >> 2, seg = slot & 3;
      async_copy16(A + (size_t)(m0 + row) * K + k0 + seg * 8, As + (size_t)(i * 256 + wid * 64) * 8);
      async_copy16(B + (size_t)(n0 + row) * K + k0 + seg * 8, Bs + (size_t)(i * 256 + wid * 64) * 8);
    }
    asm volatile("s_waitcnt vmcnt(0)" ::: "memory");
    __syncthreads();

    u16x8 af[4], bfr[4];
#pragma unroll
    for (int mi = 0; mi < 4; mi++)
      af[mi] = *(const u16x8*)(As + (wr * 64 + mi * 16 + (lane & 15)) * 32 + (lane >> 4) * 8);
#pragma unroll
    for (int ni = 0; ni < 4; ni++)
      bfr[ni] = *(const u16x8*)(Bs + (wc * 64 + ni * 16 + (lane & 15)) * 32 + (lane >> 4) * 8);
#pragma unroll
    for (int mi = 0; mi < 4; mi++)
#pragma unroll
      for (int ni = 0; ni < 4; ni++)
        acc[mi][ni] = mfma16(af[mi], bfr[ni], acc[mi][ni]);
    __syncthreads();
  }

  if (z == 3) {
    // V^T layout: [b*8+h][c_in (160)][s (2048)]
#pragma unroll
    for (int mi = 0; mi < 4; mi++)
#pragma unroll
      for (int ni = 0; ni < 4; ni++) {
        int row0 = m0 + wr * 64 + mi * 16 + ((lane >> 4) << 2);  // 4 consecutive tokens
        int col = n0 + wc * 64 + ni * 16 + (lane & 15);
        int b = row0 >> 11, s = row0 & 2047;
        int h = col / 160, c_in = col - h * 160;
        u16x4 v = {f2b(acc[mi][ni][0]), f2b(acc[mi][ni][1]),
                   f2b(acc[mi][ni][2]), f2b(acc[mi][ni][3])};
        *(u16x4*)(VTout + ((size_t)(b * 8 + h) * 160 + c_in) * 2048 + s) = v;
      }
  } else {
    u16* Cb = (z == 0) ? Qa : (z == 1) ? Qp : Kout;
#pragma unroll
    for (int mi = 0; mi < 4; mi++)
#pragma unroll
      for (int ni = 0; ni < 4; ni++)
#pragma unroll
        for (int r = 0; r < 4; r++) {
          int row = m0 + wr * 64 + mi * 16 + ((lane >> 4) << 2) + r;
          int col = n0 + wc * 64 + ni * 16 + (lane & 15);
          Cb[(size_t)row * N + col] = f2b(acc[mi][ni][r]);
        }
  }
}

// ---------- 3b. Q blend: Qa = (w*Qa + (1-w)*Qp) * qscale ----------
__global__ void qblend_kernel(u16* __restrict__ Qa, const u16* __restrict__ Qp,
                              const float* __restrict__ wgate, float qscale) {
  int idx = blockIdx.x * 256 + threadIdx.x;   // vec8 index, 655360 total
  int token = idx / 160;                       // 160 vec8 per token row
  float w = wgate[token];
  u16x8 qa = *(const u16x8*)(Qa + (size_t)idx * 8);
  u16x8 qp = *(const u16x8*)(Qp + (size_t)idx * 8);
  u16x8 o;
#pragma unroll
  for (int j = 0; j < 8; j++)
    o[j] = f2b((w * b2f(qa[j]) + (1.f - w) * b2f(qp[j])) * qscale);
  *(u16x8*)(Qa + (size_t)idx * 8) = o;
}

// ---------- 4. flash attention (kv-split) ----------
// SPLIT=2: grid (512, 2); each block does 16 of 32 kv-tiles, writes f32 partials + (m,l).
// SPLIT=1: fallback, grid (512, 1), writes normalized bf16 directly.
// K staged in LDS [64][168] (pad chunk). V read DIRECT from global V^T (no LDS, no swizzle):
// drops LDS 51200->30720 B -> 4 blocks/CU with launch_bounds(256,4) (VGPR<=128) -> 16 waves/CU.
// lrow kept as per-lane partial; single 16-lane reduce in epilogue.
template <int SPLIT>
__launch_bounds__(256, 4)
__global__ void flash_kernel(const u16* __restrict__ Q, const u16* __restrict__ Kg,
                             const u16* __restrict__ VTg, u16* __restrict__ O,
                             float* __restrict__ Opart, float* __restrict__ MLbuf) {
  const int C = 1280;
  int bid = blockIdx.x;
  int qb = bid & 31, h = (bid >> 5) & 7, b = bid >> 8;
  int sp = (SPLIT > 1) ? (int)blockIdx.y : 0;
  int tid = threadIdx.x, wid = tid >> 6, lane = tid & 63;

  const size_t baseQ = ((size_t)(b * 2048 + qb * 64)) * C + h * 160;
  const size_t baseK = ((size_t)(b * 2048)) * C + h * 160;
  const u16* Vb = VTg + (size_t)(b * 8 + h) * 160 * 2048;

  __shared__ u16 Ks[64 * 168];    // 21504 B
  __shared__ u16 Ps[4 * 16 * 72]; // 9216 B

  u16x8 qf[5];
  {
    int row = wid * 16 + (lane & 15);
    const u16* qrow = Q + baseQ + (size_t)row * C;
#pragma unroll
    for (int ks = 0; ks < 5; ks++)
      qf[ks] = *(const u16x8*)(qrow + ks * 32 + (lane >> 4) * 8);
  }

  f32x4 zero = {0.f, 0.f, 0.f, 0.f};
  f32x4 oacc[10];
#pragma unroll
  for (int i = 0; i < 10; i++) oacc[i] = zero;
  float mrow[4], lrow[4];
#pragma unroll
  for (int r = 0; r < 4; r++) { mrow[r] = -1e30f; lrow[r] = 0.f; }

  const int NT = 32 / SPLIT;
  for (int kti = 0; kti < NT; kti++) {
    int kv0 = (sp * NT + kti) * 64;
    // stage K: 21 instrs of 64x16B, linear dest, junk in pad chunk
    for (int i = wid; i < 21; i += 4) {
      int gc = i * 64 + lane;
      int r = gc / 21, ch = gc - r * 21;
      int chs = ch < 20 ? ch : 19;
      async_copy16(Kg + baseK + (size_t)(kv0 + r) * C + chs * 8, Ks + i * 512);
    }
    asm volatile("s_waitcnt vmcnt(0)" ::: "memory");
    __syncthreads();

    // scores: 16 q-rows x 64 kv (log2 domain; scale folded into Q)
    f32x4 sc[4];
#pragma unroll
    for (int ct = 0; ct < 4; ct++) {
      f32x4 a = zero;
#pragma unroll
      for (int ks = 0; ks < 5; ks++) {
        u16x8 kf = *(const u16x8*)(&Ks[(ct * 16 + (lane & 15)) * 168 + ks * 32 + (lane >> 4) * 8]);
        a = mfma16(qf[ks], kf, a);
      }
      sc[ct] = a;
    }

    // online softmax (defer-max, THR=8 in log2 units); lrow is PER-LANE partial
    float mx[4];
#pragma unroll
    for (int r = 0; r < 4; r++) {
      float m = fmaxf(fmaxf(sc[0][r], sc[1][r]), fmaxf(sc[2][r], sc[3][r]));
#pragma unroll
      for (int off = 1; off < 16; off <<= 1) m = fmaxf(m, __shfl_xor(m, off));
      mx[r] = m;
    }
    bool need = (mx[0] > mrow[0] + 8.f) || (mx[1] > mrow[1] + 8.f) ||
                (mx[2] > mrow[2] + 8.f) || (mx[3] > mrow[3] + 8.f);
    if (__any(need)) {
#pragma unroll
      for (int r = 0; r < 4; r++) {
        float mnew = fmaxf(mrow[r], mx[r]);
        float alpha = EXP2F(mrow[r] - mnew);
        mrow[r] = mnew;
        float rs = 0.f;
#pragma unroll
        for (int ct = 0; ct < 4; ct++) {
          float p = EXP2F(sc[ct][r] - mnew);
          sc[ct][r] = p;
          rs += p;
        }
        lrow[r] = lrow[r] * alpha + rs;   // alpha is lane-uniform within the row group
#pragma unroll
        for (int ci = 0; ci < 10; ci++) oacc[ci][r] *= alpha;
      }
    } else {
#pragma unroll
      for (int r = 0; r < 4; r++) {
        float rs = 0.f;
#pragma unroll
        for (int ct = 0; ct < 4; ct++) {
          float p = EXP2F(sc[ct][r] - mrow[r]);
          sc[ct][r] = p;
          rs += p;
        }
        lrow[r] += rs;
      }
    }

    // P -> LDS (per-wave private)
#pragma unroll
    for (int ct = 0; ct < 4; ct++)
#pragma unroll
      for (int r = 0; r < 4; r++)
        Ps[wid * 16 * 72 + (((lane >> 4) << 2) + r) * 72 + ct * 16 + (lane & 15)] = f2b(sc[ct][r]);

    // PV: V fragments straight from global V^T (contiguous 16B per lane)
    const u16* vp = Vb + (size_t)(lane & 15) * 2048 + kv0 + (lane >> 4) * 8;
#pragma unroll
    for (int kt2 = 0; kt2 < 2; kt2++) {
      u16x8 pf = *(const u16x8*)(&Ps[wid * 16 * 72 + (lane & 15) * 72 + kt2 * 32 + (lane >> 4) * 8]);
#pragma unroll
      for (int ci = 0; ci < 10; ci++) {
        u16x8 vf = *(const u16x8*)(vp + (size_t)ci * 16 * 2048 + kt2 * 32);
        oacc[ci] = mfma16(pf, vf, oacc[ci]);
      }
    }
    __syncthreads();
  }

  // single deferred l reduce across the 16-lane row group
#pragma unroll
  for (int r = 0; r < 4; r++)
#pragma unroll
    for (int off = 1; off < 16; off <<= 1) lrow[r] += __shfl_xor(lrow[r], off);

  int row0 = qb * 64 + wid * 16 + ((lane >> 4) << 2);
  if constexpr (SPLIT > 1) {
    size_t g0 = (size_t)(sp * 4096 + b * 2048 + row0);
#pragma unroll
    for (int ci = 0; ci < 10; ci++) {
      int col = h * 160 + ci * 16 + (lane & 15);
#pragma unroll
      for (int r = 0; r < 4; r++)
        Opart[(g0 + r) * 1280 + col] = oacc[ci][r];
    }
    if ((lane & 15) == 0) {
#pragma unroll
      for (int r = 0; r < 4; r++) {
        size_t mi = ((g0 + r) * 8 + h) * 2;
        MLbuf[mi] = mrow[r];
        MLbuf[mi + 1] = lrow[r];
      }
    }
  } else {
#pragma unroll
    for (int ci = 0; ci < 10; ci++) {
      int col = h * 160 + ci * 16 + (lane & 15);
#pragma unroll
      for (int r = 0; r < 4; r++) {
        float v = oacc[ci][r] / lrow[r];
        O[((size_t)(b * 2048) + row0 + r) * C + col] = f2b(v);
      }
    }
  }
}

// ---------- 4b. combine the two kv-split halves ----------
__global__ void combine_kernel(const float* __restrict__ Opart, const float* __restrict__ MLbuf,
                               u16* __restrict__ O) {
  int g = blockIdx.x;       // token row 0..4095
  int tid = threadIdx.x;    // 256
  __shared__ float w0s[8], w1s[8], li[8];
  if (tid < 8) {
    size_t i0 = ((size_t)g * 8 + tid) * 2;
    size_t i1 = ((size_t)(4096 + g) * 8 + tid) * 2;
    float m0 = MLbuf[i0], l0 = MLbuf[i0 + 1];
    float m1 = MLbuf[i1], l1 = MLbuf[i1 + 1];
    float m = fmaxf(m0, m1);
    float a0 = EXP2F(m0 - m), a1 = EXP2F(m1 - m);
    w0s[tid] = a0; w1s[tid] = a1;
    li[tid] = 1.f / (l0 * a0 + l1 * a1);
  }
  __syncthreads();
#pragma unroll
  for (int i = 0; i < 5; i++) {
    int c = i * 256 + tid;
    int h = c / 160;
    float v0 = Opart[(size_t)g * 1280 + c];
    float v1 = Opart[(size_t)(4096 + g) * 1280 + c];
    O[(size_t)g * 1280 + c] = f2b((v0 * w0s[h] + v1 * w1s[h]) * li[h]);
  }
}

// ---------- 5. out-proj GEMM: C = A@B0 + bias + resid -> fp32 ----------
__launch_bounds__(256)
__global__ void gemm_out_kernel(const u16* __restrict__ A, const u16* __restrict__ Bt,
                                float* __restrict__ Cf, const float* __restrict__ bias,
                                const float* __restrict__ resid) {
  const int K = 1280, N = 1280;
  __shared__ u16 As[128 * 32];
  __shared__ u16 Bs[128 * 32];

  int tid = threadIdx.x;
  int wid = tid >> 6, lane = tid & 63;
  int nb = blockIdx.x, mb = blockIdx.y;
  int m0 = mb * 128, n0 = nb * 128;

  f32x4 zero = {0.f, 0.f, 0.f, 0.f};
  f32x4 acc[4][4];
#pragma unroll
  for (int i = 0; i < 4; i++)
#pragma unroll
    for (int j = 0; j < 4; j++) acc[i][j] = zero;

  int wr = wid >> 1, wc = wid & 1;

  for (int kk = 0; kk < 40; kk++) {
    int k0 = kk * 32;
#pragma unroll
    for (int i = 0; i < 2; i++) {
      int slot = i * 256 + tid;
      int row = slot >> 2, seg = slot & 3;
      async_copy16(A + (size_t)(m0 + row) * K + k0 + seg * 8, As + (size_t)(i * 256 + wid * 64) * 8);
      async_copy16(Bt + (size_t)(n0 + row) * K + k0 + seg * 8, Bs + (size_t)(i * 256 + wid * 64) * 8);
    }
    asm volatile("s_waitcnt vmcnt(0)" ::: "memory");
    __syncthreads();

    u16x8 af[4], bfr[4];
#pragma unroll
    for (int mi = 0; mi < 4; mi++)
      af[mi] = *(const u16x8*)(As + (wr * 64 + mi * 16 + (lane & 15)) * 32 + (lane >> 4) * 8);
#pragma unroll
    for (int ni = 0; ni < 4; ni++)
      bfr[ni] = *(const u16x8*)(Bs + (wc * 64 + ni * 16 + (lane & 15)) * 32 + (lane >> 4) * 8);
#pragma unroll
    for (int mi = 0; mi < 4; mi++)
#pragma unroll
      for (int ni = 0; ni < 4; ni++)
        acc[mi][ni] = mfma16(af[mi], bfr[ni], acc[mi][ni]);
    __syncthreads();
  }

#pragma unroll
  for (int mi = 0; mi < 4; mi++)
#pragma unroll
    for (int ni = 0; ni < 4; ni++)
#pragma unroll
      for (int r = 0; r < 4; r++) {
        int row = m0 + wr * 64 + mi * 16 + ((lane >> 4) << 2) + r;
        int col = n0 + wc * 64 + ni * 16 + (lane & 15);
        Cf[(size_t)row * N + col] = acc[mi][ni][r] + bias[col] + resid[(size_t)row * N + col];
      }
}

// ---------- launch ----------
extern "C" void kernel_launch(void* const* d_in, const int* in_sizes, int n_in,
                              void* d_out, int out_size, void* d_ws, size_t ws_size,
                              hipStream_t stream) {
  const float* hs      = (const float*)d_in[0];
  const float* mask    = (const float*)d_in[1];
  const float* attn_wq = (const float*)d_in[2];
  const float* attn_wk = (const float*)d_in[3];
  const float* attn_wv = (const float*)d_in[4];
  const float* out_w   = (const float*)d_in[5];
  const float* out_b   = (const float*)d_in[6];
  const float* proc_wq = (const float*)d_in[7];
  const float* proc_wk = (const float*)d_in[8];
  const float* proc_wv = (const float*)d_in[9];
  const float* ww      = (const float*)d_in[10];
  const float* wb      = (const float*)d_in[11];
  float* out = (float*)d_out;

  char* ws = (char*)d_ws;
  const size_t TOK = (size_t)4096 * 1280;     // tokens x channels
  u16* hsb = (u16*)(ws);
  u16* Qb  = (u16*)(ws + 2 * TOK);
  u16* Kb  = (u16*)(ws + 4 * TOK);
  u16* VTb = (u16*)(ws + 6 * TOK);            // V^T [16][160][2048]
  u16* AOb = (u16*)(ws + 8 * TOK);            // doubles as Qp temp before flash
  u16* Wt  = (u16*)(ws + 10 * TOK);           // 7 x 1280x1280 bf16
  float* wgate = (float*)(ws + 10 * TOK + (size_t)7 * 1280 * 1280 * 2);
  char* extra = ws + 10 * TOK + (size_t)7 * 1280 * 1280 * 2 + 16384;
  float* Opart = (float*)extra;                               // [2][4096][1280] f32
  float* MLbuf = (float*)(extra + (size_t)2 * 4096 * 1280 * 4); // [2][4096][8]{m,l}
  size_t need = (size_t)(extra - ws) + (size_t)2 * 4096 * 1280 * 4 + (size_t)2 * 4096 * 8 * 8;

  prep_kernel<<<4096, 256, 0, stream>>>(hs, mask, ww, wb, hsb, wgate);
  wtrans_kernel<<<dim3(40, 40, 7), 256, 0, stream>>>(attn_wq, attn_wk, attn_wv, out_w,
                                                     proc_wq, proc_wk, proc_wv, Wt);
  const size_t WSZ = (size_t)1280 * 1280;
  // merged Qa/Qp/K/V GEMM: 1280 uniform blocks, ~5 blocks/CU target
  gemm_qkv_kernel<<<dim3(10, 32, 4), 256, 0, stream>>>(hsb, Wt, Qb, AOb, Kb, VTb);
  // 1/sqrt(160) * log2(e): scores land in log2 domain
  const float qscale = 0.11405505533858971f;
  qblend_kernel<<<2560, 256, 0, stream>>>(Qb, AOb, wgate, qscale);

  if (ws_size >= need) {
    flash_kernel<2><<<dim3(512, 2), 256, 0, stream>>>(Qb, Kb, VTb, nullptr, Opart, MLbuf);
    combine_kernel<<<4096, 256, 0, stream>>>(Opart, MLbuf, AOb);
  } else {
    flash_kernel<1><<<dim3(512, 1), 256, 0, stream>>>(Qb, Kb, VTb, AOb, nullptr, nullptr);
  }
  gemm_out_kernel<<<dim3(10, 32), 256, 0, stream>>>(AOb, Wt + 3 * WSZ, out, out_b, hs);
}

// Round 2
// 261.474 us; speedup vs baseline: 1.6386x; 1.6386x over previous
//
#include <hip/hip_runtime.h>

typedef unsigned short u16;
typedef u16 u16x4 __attribute__((ext_vector_type(4)));
typedef u16 u16x8 __attribute__((ext_vector_type(8)));
typedef __bf16 bf16x8 __attribute__((ext_vector_type(8)));
typedef float f32x4 __attribute__((ext_vector_type(4)));

#define DEVI __device__ __forceinline__

#if __has_builtin(__builtin_amdgcn_exp2f)
#define EXP2F __builtin_amdgcn_exp2f
#else
#define EXP2F exp2f
#endif

// ---------- helpers ----------
DEVI u16 f2b(float f) {  // fp32 -> bf16 RNE
  unsigned u = __builtin_bit_cast(unsigned, f);
  u += 0x7fffu + ((u >> 16) & 1u);
  return (u16)(u >> 16);
}

DEVI float b2f(u16 v) { return __builtin_bit_cast(float, (unsigned)v << 16); }

DEVI f32x4 mfma16(u16x8 a, u16x8 b, f32x4 c) {
  return __builtin_amdgcn_mfma_f32_16x16x32_bf16(
      __builtin_bit_cast(bf16x8, a), __builtin_bit_cast(bf16x8, b), c, 0, 0, 0);
}

DEVI void async_copy16(const u16* g, u16* l) {
  __builtin_amdgcn_global_load_lds(
      (__attribute__((address_space(1))) unsigned int*)(g),
      (__attribute__((address_space(3))) unsigned int*)(l), 16, 0, 0);
}

// ---------- 1. hs->bf16 + gate ----------
__global__ void prep_kernel(const float* __restrict__ hs, const float* __restrict__ mask,
                            const float* __restrict__ ww, const float* __restrict__ wb,
                            u16* __restrict__ hsb, float* __restrict__ wgate) {
  int token = blockIdx.x;            // 0..4095
  int tid = threadIdx.x;             // 256
  const float* row = hs + (size_t)token * 1280;
  u16* orow = hsb + (size_t)token * 1280;
  float acc = 0.f;
#pragma unroll
  for (int i = 0; i < 5; i++) {
    int c = i * 256 + tid;
    float v = row[c];
    orow[c] = f2b(v);
    acc += v * ww[c];
  }
#pragma unroll
  for (int off = 1; off < 64; off <<= 1) acc += __shfl_xor(acc, off);
  __shared__ float partial[4];
  int wid = tid >> 6;
  if ((tid & 63) == 0) partial[wid] = acc;
  __syncthreads();
  if (tid == 0) {
    float tot = partial[0] + partial[1] + partial[2] + partial[3];
    int b = token >> 11, t = token & 2047;
    int s = t & 1023;
    float mv = mask[b * 65536 + ((s >> 5) * 8) * 256 + (s & 31) * 8];
    float z = tot + mv * ww[1280] + wb[0];
    wgate[token] = 1.f / (1.f + __expf(-z));
  }
}

// ---------- 2. weight transpose + bf16 ----------
__global__ void wtrans_kernel(const float* w0, const float* w1, const float* w2,
                              const float* w3, const float* w4, const float* w5,
                              const float* w6, u16* __restrict__ out) {
  const float* src;
  switch (blockIdx.z) {
    case 0: src = w0; break; case 1: src = w1; break; case 2: src = w2; break;
    case 3: src = w3; break; case 4: src = w4; break; case 5: src = w5; break;
    default: src = w6; break;
  }
  u16* dst = out + (size_t)blockIdx.z * 1280 * 1280;
  __shared__ float tile[32][33];
  int tx = threadIdx.x & 31, ty = threadIdx.x >> 5;   // 32x8
  int k0 = blockIdx.x * 32, n0 = blockIdx.y * 32;
#pragma unroll
  for (int r = 0; r < 4; r++)
    tile[ty + r * 8][tx] = src[(size_t)(k0 + ty + r * 8) * 1280 + n0 + tx];
  __syncthreads();
#pragma unroll
  for (int r = 0; r < 4; r++)
    dst[(size_t)(n0 + ty + r * 8) * 1280 + k0 + tx] = f2b(tile[tx][ty + r * 8]);
}

// ---------- 3. merged QKV GEMM: 4 uniform 128x128 tile jobs per (nb,mb) ----------
// z=0: A@attn_wq -> Qa ; z=1: A@proc_wq -> Qp ; z=2: K (half-selected) -> Kb row-major
// z=3: V (half-selected) -> VTb transposed [b*8+h][160][2048]
__launch_bounds__(256)
__global__ void gemm_qkv_kernel(const u16* __restrict__ A, const u16* __restrict__ Wt,
                                u16* __restrict__ Qa, u16* __restrict__ Qp,
                                u16* __restrict__ Kout, u16* __restrict__ VTout) {
  const int K = 1280, N = 1280;
  const size_t WSZ = (size_t)1280 * 1280;
  __shared__ u16 As[128 * 32];
  __shared__ u16 Bs[128 * 32];

  int tid = threadIdx.x;
  int wid = tid >> 6, lane = tid & 63;
  int nb = blockIdx.x, mb = blockIdx.y, z = blockIdx.z;
  int m0 = mb * 128, n0 = nb * 128;
  bool first = ((m0 & 2047) < 1024);   // first half of sequence -> attn weights

  const u16* B;
  switch (z) {
    case 0:  B = Wt + 0 * WSZ; break;
    case 1:  B = Wt + 4 * WSZ; break;
    case 2:  B = first ? Wt + 1 * WSZ : Wt + 5 * WSZ; break;
    default: B = first ? Wt + 2 * WSZ : Wt + 6 * WSZ; break;
  }

  f32x4 zero = {0.f, 0.f, 0.f, 0.f};
  f32x4 acc[4][4];
#pragma unroll
  for (int i = 0; i < 4; i++)
#pragma unroll
    for (int j = 0; j < 4; j++) acc[i][j] = zero;

  int wr = wid >> 1, wc = wid & 1;

  for (int kk = 0; kk < 40; kk++) {
    int k0 = kk * 32;
#pragma unroll
    for (int i = 0; i < 2; i++) {
      int slot = i * 256 + tid;
      int row = slot >> 2, seg = slot & 3;
      async_copy16(A + (size_t)(m0 + row) * K + k0 + seg * 8, As + (size_t)(i * 256 + wid * 64) * 8);
      async_copy16(B + (size_t)(n0 + row) * K + k0 + seg * 8, Bs + (size_t)(i * 256 + wid * 64) * 8);
    }
    asm volatile("s_waitcnt vmcnt(0)" ::: "memory");
    __syncthreads();

    u16x8 af[4], bfr[4];
#pragma unroll
    for (int mi = 0; mi < 4; mi++)
      af[mi] = *(const u16x8*)(As + (wr * 64 + mi * 16 + (lane & 15)) * 32 + (lane >> 4) * 8);
#pragma unroll
    for (int ni = 0; ni < 4; ni++)
      bfr[ni] = *(const u16x8*)(Bs + (wc * 64 + ni * 16 + (lane & 15)) * 32 + (lane >> 4) * 8);
#pragma unroll
    for (int mi = 0; mi < 4; mi++)
#pragma unroll
      for (int ni = 0; ni < 4; ni++)
        acc[mi][ni] = mfma16(af[mi], bfr[ni], acc[mi][ni]);
    __syncthreads();
  }

  if (z == 3) {
    // V^T layout: [b*8+h][c_in (160)][s (2048)]
#pragma unroll
    for (int mi = 0; mi < 4; mi++)
#pragma unroll
      for (int ni = 0; ni < 4; ni++) {
        int row0 = m0 + wr * 64 + mi * 16 + ((lane >> 4) << 2);  // 4 consecutive tokens
        int col = n0 + wc * 64 + ni * 16 + (lane & 15);
        int b = row0 >> 11, s = row0 & 2047;
        int h = col / 160, c_in = col - h * 160;
        u16x4 v = {f2b(acc[mi][ni][0]), f2b(acc[mi][ni][1]),
                   f2b(acc[mi][ni][2]), f2b(acc[mi][ni][3])};
        *(u16x4*)(VTout + ((size_t)(b * 8 + h) * 160 + c_in) * 2048 + s) = v;
      }
  } else {
    u16* Cb = (z == 0) ? Qa : (z == 1) ? Qp : Kout;
#pragma unroll
    for (int mi = 0; mi < 4; mi++)
#pragma unroll
      for (int ni = 0; ni < 4; ni++)
#pragma unroll
        for (int r = 0; r < 4; r++) {
          int row = m0 + wr * 64 + mi * 16 + ((lane >> 4) << 2) + r;
          int col = n0 + wc * 64 + ni * 16 + (lane & 15);
          Cb[(size_t)row * N + col] = f2b(acc[mi][ni][r]);
        }
  }
}

// ---------- 3b. Q blend: Qa = (w*Qa + (1-w)*Qp) * qscale ----------
__global__ void qblend_kernel(u16* __restrict__ Qa, const u16* __restrict__ Qp,
                              const float* __restrict__ wgate, float qscale) {
  int idx = blockIdx.x * 256 + threadIdx.x;   // vec8 index, 655360 total
  int token = idx / 160;                       // 160 vec8 per token row
  float w = wgate[token];
  u16x8 qa = *(const u16x8*)(Qa + (size_t)idx * 8);
  u16x8 qp = *(const u16x8*)(Qp + (size_t)idx * 8);
  u16x8 o;
#pragma unroll
  for (int j = 0; j < 8; j++)
    o[j] = f2b((w * b2f(qa[j]) + (1.f - w) * b2f(qp[j])) * qscale);
  *(u16x8*)(Qa + (size_t)idx * 8) = o;
}

// ---------- 4. flash attention (kv-split, LDS-staged V) ----------
// SPLIT=2: grid (512,2); each block does 16 of 32 kv-tiles and writes
// l-normalized bf16 partials + (m,l) per row. SPLIT=1: round-0 behavior.
// Round-1 lessons: V MUST be LDS-staged (direct-global V = 4x per-wave dup,
// FETCH 87->485 MB); VGPRs MUST NOT be capped (launch_bounds(256,4) -> 64 VGPR
// -> oacc spill, WRITE 10->413 MB). LDS 51200 B -> 3 blocks/CU, 12 waves/CU.
template <int SPLIT>
__launch_bounds__(256)
__global__ void flash_kernel(const u16* __restrict__ Q, const u16* __restrict__ Kg,
                             const u16* __restrict__ VTg, u16* __restrict__ O,
                             u16* __restrict__ Opart, float* __restrict__ MLbuf) {
  const int C = 1280;
  int bid = blockIdx.x;
  int qb = bid & 31, h = (bid >> 5) & 7, b = bid >> 8;
  int sp = (SPLIT > 1) ? (int)blockIdx.y : 0;
  int tid = threadIdx.x, wid = tid >> 6, lane = tid & 63;

  const size_t baseQ = ((size_t)(b * 2048 + qb * 64)) * C + h * 160;
  const size_t baseK = ((size_t)(b * 2048)) * C + h * 160;
  const size_t baseVT = (size_t)(b * 8 + h) * 160 * 2048;

  __shared__ u16 Ks[64 * 168];    // 21504 B
  __shared__ u16 Vts[160 * 64];   // 20480 B, chunk-swizzled
  __shared__ u16 Ps[4 * 16 * 72]; // 9216 B

  u16x8 qf[5];
  {
    int row = wid * 16 + (lane & 15);
    const u16* qrow = Q + baseQ + (size_t)row * C;
#pragma unroll
    for (int ks = 0; ks < 5; ks++)
      qf[ks] = *(const u16x8*)(qrow + ks * 32 + (lane >> 4) * 8);
  }

  f32x4 zero = {0.f, 0.f, 0.f, 0.f};
  f32x4 oacc[10];
#pragma unroll
  for (int i = 0; i < 10; i++) oacc[i] = zero;
  float mrow[4], lrow[4];
#pragma unroll
  for (int r = 0; r < 4; r++) { mrow[r] = -1e30f; lrow[r] = 0.f; }

  const int NT = 32 / SPLIT;
  for (int kti = 0; kti < NT; kti++) {
    int kv0 = (sp * NT + kti) * 64;
    // stage K: 21 instrs of 64x16B, linear dest, junk in pad chunk
    for (int i = wid; i < 21; i += 4) {
      int gc = i * 64 + lane;
      int r = gc / 21, ch = gc - r * 21;
      int chs = ch < 20 ? ch : 19;
      async_copy16(Kg + baseK + (size_t)(kv0 + r) * C + chs * 8, Ks + i * 512);
    }
    // stage V^T: 20 instrs, source pre-swizzled so read-side XOR is conflict-free
    for (int i = wid; i < 20; i += 4) {
      int gc = i * 64 + lane;
      int c = gc >> 3, j = gc & 7;
      async_copy16(VTg + baseVT + (size_t)c * 2048 + kv0 + ((j ^ (c & 7)) << 3), Vts + i * 512);
    }
    asm volatile("s_waitcnt vmcnt(0)" ::: "memory");
    __syncthreads();

    // scores: 16 q-rows x 64 kv (log2 domain; scale folded into Q)
    f32x4 sc[4];
#pragma unroll
    for (int ct = 0; ct < 4; ct++) {
      f32x4 a = zero;
#pragma unroll
      for (int ks = 0; ks < 5; ks++) {
        u16x8 kf = *(const u16x8*)(&Ks[(ct * 16 + (lane & 15)) * 168 + ks * 32 + (lane >> 4) * 8]);
        a = mfma16(qf[ks], kf, a);
      }
      sc[ct] = a;
    }

    // online softmax (defer-max, THR=8 in log2 units); lrow is PER-LANE partial
    float mx[4];
#pragma unroll
    for (int r = 0; r < 4; r++) {
      float m = fmaxf(fmaxf(sc[0][r], sc[1][r]), fmaxf(sc[2][r], sc[3][r]));
#pragma unroll
      for (int off = 1; off < 16; off <<= 1) m = fmaxf(m, __shfl_xor(m, off));
      mx[r] = m;
    }
    bool need = (mx[0] > mrow[0] + 8.f) || (mx[1] > mrow[1] + 8.f) ||
                (mx[2] > mrow[2] + 8.f) || (mx[3] > mrow[3] + 8.f);
    if (__any(need)) {
#pragma unroll
      for (int r = 0; r < 4; r++) {
        float mnew = fmaxf(mrow[r], mx[r]);
        float alpha = EXP2F(mrow[r] - mnew);
        mrow[r] = mnew;
        float rs = 0.f;
#pragma unroll
        for (int ct = 0; ct < 4; ct++) {
          float p = EXP2F(sc[ct][r] - mnew);
          sc[ct][r] = p;
          rs += p;
        }
        lrow[r] = lrow[r] * alpha + rs;   // alpha lane-uniform; reduce deferred to epilogue
#pragma unroll
        for (int ci = 0; ci < 10; ci++) oacc[ci][r] *= alpha;
      }
    } else {
#pragma unroll
      for (int r = 0; r < 4; r++) {
        float rs = 0.f;
#pragma unroll
        for (int ct = 0; ct < 4; ct++) {
          float p = EXP2F(sc[ct][r] - mrow[r]);
          sc[ct][r] = p;
          rs += p;
        }
        lrow[r] += rs;
      }
    }

    // P -> LDS (per-wave private), then PV
#pragma unroll
    for (int ct = 0; ct < 4; ct++)
#pragma unroll
      for (int r = 0; r < 4; r++)
        Ps[wid * 16 * 72 + (((lane >> 4) << 2) + r) * 72 + ct * 16 + (lane & 15)] = f2b(sc[ct][r]);

#pragma unroll
    for (int kt2 = 0; kt2 < 2; kt2++) {
      u16x8 pf = *(const u16x8*)(&Ps[wid * 16 * 72 + (lane & 15) * 72 + kt2 * 32 + (lane >> 4) * 8]);
#pragma unroll
      for (int ci = 0; ci < 10; ci++) {
        int c = ci * 16 + (lane & 15);
        int jl = kt2 * 4 + (lane >> 4);
        u16x8 vf = *(const u16x8*)(&Vts[c * 64 + ((jl ^ (c & 7)) << 3)]);
        oacc[ci] = mfma16(pf, vf, oacc[ci]);
      }
    }
    __syncthreads();
  }

  // single deferred l reduce across the 16-lane row group
#pragma unroll
  for (int r = 0; r < 4; r++)
#pragma unroll
    for (int off = 1; off < 16; off <<= 1) lrow[r] += __shfl_xor(lrow[r], off);

  int row0 = qb * 64 + wid * 16 + ((lane >> 4) << 2);
  if constexpr (SPLIT > 1) {
    // l-normalized bf16 partials (values O(1), bf16-safe) + (m,l) per row/head
    float linv[4];
#pragma unroll
    for (int r = 0; r < 4; r++) linv[r] = 1.f / lrow[r];
    size_t g0 = (size_t)sp * 4096 + (size_t)b * 2048 + row0;
#pragma unroll
    for (int ci = 0; ci < 10; ci++) {
      int col = h * 160 + ci * 16 + (lane & 15);
#pragma unroll
      for (int r = 0; r < 4; r++)
        Opart[(g0 + r) * 1280 + col] = f2b(oacc[ci][r] * linv[r]);
    }
    if ((lane & 15) == 0) {
#pragma unroll
      for (int r = 0; r < 4; r++) {
        size_t mi = ((g0 + r) * 8 + h) * 2;
        MLbuf[mi] = mrow[r];
        MLbuf[mi + 1] = lrow[r];
      }
    }
  } else {
#pragma unroll
    for (int ci = 0; ci < 10; ci++) {
      int col = h * 160 + ci * 16 + (lane & 15);
#pragma unroll
      for (int r = 0; r < 4; r++) {
        float v = oacc[ci][r] / lrow[r];
        O[((size_t)(b * 2048) + row0 + r) * C + col] = f2b(v);
      }
    }
  }
}

// ---------- 4b. combine the two kv-split halves (vec8) ----------
// O = (v0*a0*l0 + v1*a1*l1) / (a0*l0 + a1*l1), a_i = 2^(m_i - max(m))
__global__ void combine_kernel(const u16* __restrict__ Opart, const float* __restrict__ MLbuf,
                               u16* __restrict__ O) {
  int idx = blockIdx.x * 256 + threadIdx.x;   // vec8 index, 655360 total
  int token = idx / 160;
  int h = (idx - token * 160) / 20;
  size_t i0 = ((size_t)token * 8 + h) * 2;
  size_t i1 = ((size_t)(4096 + token) * 8 + h) * 2;
  float m0 = MLbuf[i0], l0 = MLbuf[i0 + 1];
  float m1 = MLbuf[i1], l1 = MLbuf[i1 + 1];
  float m = fmaxf(m0, m1);
  float w0 = EXP2F(m0 - m) * l0, w1 = EXP2F(m1 - m) * l1;
  float inv = 1.f / (w0 + w1);
  w0 *= inv; w1 *= inv;
  u16x8 a = *(const u16x8*)(Opart + (size_t)idx * 8);
  u16x8 c = *(const u16x8*)(Opart + (size_t)(655360 + idx) * 8);
  u16x8 o;
#pragma unroll
  for (int j = 0; j < 8; j++)
    o[j] = f2b(b2f(a[j]) * w0 + b2f(c[j]) * w1);
  *(u16x8*)(O + (size_t)idx * 8) = o;
}

// ---------- 5. out-proj GEMM: C = A@B0 + bias + resid -> fp32 ----------
__launch_bounds__(256)
__global__ void gemm_out_kernel(const u16* __restrict__ A, const u16* __restrict__ Bt,
                                float* __restrict__ Cf, const float* __restrict__ bias,
                                const float* __restrict__ resid) {
  const int K = 1280, N = 1280;
  __shared__ u16 As[128 * 32];
  __shared__ u16 Bs[128 * 32];

  int tid = threadIdx.x;
  int wid = tid >> 6, lane = tid & 63;
  int nb = blockIdx.x, mb = blockIdx.y;
  int m0 = mb * 128, n0 = nb * 128;

  f32x4 zero = {0.f, 0.f, 0.f, 0.f};
  f32x4 acc[4][4];
#pragma unroll
  for (int i = 0; i < 4; i++)
#pragma unroll
    for (int j = 0; j < 4; j++) acc[i][j] = zero;

  int wr = wid >> 1, wc = wid & 1;

  for (int kk = 0; kk < 40; kk++) {
    int k0 = kk * 32;
#pragma unroll
    for (int i = 0; i < 2; i++) {
      int slot = i * 256 + tid;
      int row = slot >> 2, seg = slot & 3;
      async_copy16(A + (size_t)(m0 + row) * K + k0 + seg * 8, As + (size_t)(i * 256 + wid * 64) * 8);
      async_copy16(Bt + (size_t)(n0 + row) * K + k0 + seg * 8, Bs + (size_t)(i * 256 + wid * 64) * 8);
    }
    asm volatile("s_waitcnt vmcnt(0)" ::: "memory");
    __syncthreads();

    u16x8 af[4], bfr[4];
#pragma unroll
    for (int mi = 0; mi < 4; mi++)
      af[mi] = *(const u16x8*)(As + (wr * 64 + mi * 16 + (lane & 15)) * 32 + (lane >> 4) * 8);
#pragma unroll
    for (int ni = 0; ni < 4; ni++)
      bfr[ni] = *(const u16x8*)(Bs + (wc * 64 + ni * 16 + (lane & 15)) * 32 + (lane >> 4) * 8);
#pragma unroll
    for (int mi = 0; mi < 4; mi++)
#pragma unroll
      for (int ni = 0; ni < 4; ni++)
        acc[mi][ni] = mfma16(af[mi], bfr[ni], acc[mi][ni]);
    __syncthreads();
  }

#pragma unroll
  for (int mi = 0; mi < 4; mi++)
#pragma unroll
    for (int ni = 0; ni < 4; ni++)
#pragma unroll
      for (int r = 0; r < 4; r++) {
        int row = m0 + wr * 64 + mi * 16 + ((lane >> 4) << 2) + r;
        int col = n0 + wc * 64 + ni * 16 + (lane & 15);
        Cf[(size_t)row * N + col] = acc[mi][ni][r] + bias[col] + resid[(size_t)row * N + col];
      }
}

// ---------- launch ----------
extern "C" void kernel_launch(void* const* d_in, const int* in_sizes, int n_in,
                              void* d_out, int out_size, void* d_ws, size_t ws_size,
                              hipStream_t stream) {
  const float* hs      = (const float*)d_in[0];
  const float* mask    = (const float*)d_in[1];
  const float* attn_wq = (const float*)d_in[2];
  const float* attn_wk = (const float*)d_in[3];
  const float* attn_wv = (const float*)d_in[4];
  const float* out_w   = (const float*)d_in[5];
  const float* out_b   = (const float*)d_in[6];
  const float* proc_wq = (const float*)d_in[7];
  const float* proc_wk = (const float*)d_in[8];
  const float* proc_wv = (const float*)d_in[9];
  const float* ww      = (const float*)d_in[10];
  const float* wb      = (const float*)d_in[11];
  float* out = (float*)d_out;

  char* ws = (char*)d_ws;
  const size_t TOK = (size_t)4096 * 1280;     // tokens x channels
  u16* hsb = (u16*)(ws);
  u16* Qb  = (u16*)(ws + 2 * TOK);
  u16* Kb  = (u16*)(ws + 4 * TOK);
  u16* VTb = (u16*)(ws + 6 * TOK);            // V^T [16][160][2048]
  u16* AOb = (u16*)(ws + 8 * TOK);            // doubles as Qp temp before flash
  u16* Wt  = (u16*)(ws + 10 * TOK);           // 7 x 1280x1280 bf16
  float* wgate = (float*)(ws + 10 * TOK + (size_t)7 * 1280 * 1280 * 2);
  char* extra = ws + 10 * TOK + (size_t)7 * 1280 * 1280 * 2 + 16384;
  u16* Opart = (u16*)extra;                                   // [2][4096][1280] bf16
  float* MLbuf = (float*)(extra + (size_t)2 * 4096 * 1280 * 2); // [2][4096][8]{m,l}
  size_t need = (size_t)(extra - ws) + (size_t)2 * 4096 * 1280 * 2 + (size_t)2 * 4096 * 8 * 8;

  prep_kernel<<<4096, 256, 0, stream>>>(hs, mask, ww, wb, hsb, wgate);
  wtrans_kernel<<<dim3(40, 40, 7), 256, 0, stream>>>(attn_wq, attn_wk, attn_wv, out_w,
                                                     proc_wq, proc_wk, proc_wv, Wt);
  const size_t WSZ = (size_t)1280 * 1280;
  // merged Qa/Qp/K/V GEMM: 1280 uniform blocks
  gemm_qkv_kernel<<<dim3(10, 32, 4), 256, 0, stream>>>(hsb, Wt, Qb, AOb, Kb, VTb);
  // 1/sqrt(160) * log2(e): scores land in log2 domain
  const float qscale = 0.11405505533858971f;
  qblend_kernel<<<2560, 256, 0, stream>>>(Qb, AOb, wgate, qscale);

  if (ws_size >= need) {
    flash_kernel<2><<<dim3(512, 2), 256, 0, stream>>>(Qb, Kb, VTb, nullptr, Opart, MLbuf);
    combine_kernel<<<2560, 256, 0, stream>>>(Opart, MLbuf, AOb);
  } else {
    flash_kernel<1><<<dim3(512, 1), 256, 0, stream>>>(Qb, Kb, VTb, AOb, nullptr, nullptr);
  }
  gemm_out_kernel<<<dim3(10, 32), 256, 0, stream>>>(AOb, Wt + 3 * WSZ, out, out_b, hs);
}

// Round 3
// 250.927 us; speedup vs baseline: 1.7075x; 1.0420x over previous
//
#include <hip/hip_runtime.h>

typedef unsigned short u16;
typedef u16 u16x4 __attribute__((ext_vector_type(4)));
typedef u16 u16x8 __attribute__((ext_vector_type(8)));
typedef __bf16 bf16x8 __attribute__((ext_vector_type(8)));
typedef float f32x4 __attribute__((ext_vector_type(4)));

#define DEVI __device__ __forceinline__

#if __has_builtin(__builtin_amdgcn_exp2f)
#define EXP2F __builtin_amdgcn_exp2f
#else
#define EXP2F exp2f
#endif

// ---------- helpers ----------
DEVI u16 f2b(float f) {  // fp32 -> bf16 RNE
  unsigned u = __builtin_bit_cast(unsigned, f);
  u += 0x7fffu + ((u >> 16) & 1u);
  return (u16)(u >> 16);
}

DEVI float b2f(u16 v) { return __builtin_bit_cast(float, (unsigned)v << 16); }

DEVI f32x4 mfma16(u16x8 a, u16x8 b, f32x4 c) {
  return __builtin_amdgcn_mfma_f32_16x16x32_bf16(
      __builtin_bit_cast(bf16x8, a), __builtin_bit_cast(bf16x8, b), c, 0, 0, 0);
}

DEVI void async_copy16(const u16* g, u16* l) {
  __builtin_amdgcn_global_load_lds(
      (__attribute__((address_space(1))) unsigned int*)(g),
      (__attribute__((address_space(3))) unsigned int*)(l), 16, 0, 0);
}

// raw barrier with compiler memory fences on both sides (NOT __syncthreads:
// that emits s_waitcnt vmcnt(0) and would kill the counted-vmcnt pipeline)
DEVI void fence_barrier() {
  asm volatile("" ::: "memory");
  __builtin_amdgcn_s_barrier();
  asm volatile("" ::: "memory");
}

// ---------- 1. hs->bf16 + gate ----------
__global__ void prep_kernel(const float* __restrict__ hs, const float* __restrict__ mask,
                            const float* __restrict__ ww, const float* __restrict__ wb,
                            u16* __restrict__ hsb, float* __restrict__ wgate) {
  int token = blockIdx.x;            // 0..4095
  int tid = threadIdx.x;             // 256
  const float* row = hs + (size_t)token * 1280;
  u16* orow = hsb + (size_t)token * 1280;
  float acc = 0.f;
#pragma unroll
  for (int i = 0; i < 5; i++) {
    int c = i * 256 + tid;
    float v = row[c];
    orow[c] = f2b(v);
    acc += v * ww[c];
  }
#pragma unroll
  for (int off = 1; off < 64; off <<= 1) acc += __shfl_xor(acc, off);
  __shared__ float partial[4];
  int wid = tid >> 6;
  if ((tid & 63) == 0) partial[wid] = acc;
  __syncthreads();
  if (tid == 0) {
    float tot = partial[0] + partial[1] + partial[2] + partial[3];
    int b = token >> 11, t = token & 2047;
    int s = t & 1023;
    float mv = mask[b * 65536 + ((s >> 5) * 8) * 256 + (s & 31) * 8];
    float z = tot + mv * ww[1280] + wb[0];
    wgate[token] = 1.f / (1.f + __expf(-z));
  }
}

// ---------- 2. weight transpose + bf16 ----------
__global__ void wtrans_kernel(const float* w0, const float* w1, const float* w2,
                              const float* w3, const float* w4, const float* w5,
                              const float* w6, u16* __restrict__ out) {
  const float* src;
  switch (blockIdx.z) {
    case 0: src = w0; break; case 1: src = w1; break; case 2: src = w2; break;
    case 3: src = w3; break; case 4: src = w4; break; case 5: src = w5; break;
    default: src = w6; break;
  }
  u16* dst = out + (size_t)blockIdx.z * 1280 * 1280;
  __shared__ float tile[32][33];
  int tx = threadIdx.x & 31, ty = threadIdx.x >> 5;   // 32x8
  int k0 = blockIdx.x * 32, n0 = blockIdx.y * 32;
#pragma unroll
  for (int r = 0; r < 4; r++)
    tile[ty + r * 8][tx] = src[(size_t)(k0 + ty + r * 8) * 1280 + n0 + tx];
  __syncthreads();
#pragma unroll
  for (int r = 0; r < 4; r++)
    dst[(size_t)(n0 + ty + r * 8) * 1280 + k0 + tx] = f2b(tile[tx][ty + r * 8]);
}

// ---------- 3. merged QKV GEMM: 4 uniform 128x128 tile jobs per (nb,mb) ----------
// z=0: A@attn_wq -> Qa ; z=1: A@proc_wq -> Qp ; z=2: K (half-selected) -> Kb row-major
// z=3: V (half-selected) -> VTb transposed [b*8+h][160][2048]
__launch_bounds__(256)
__global__ void gemm_qkv_kernel(const u16* __restrict__ A, const u16* __restrict__ Wt,
                                u16* __restrict__ Qa, u16* __restrict__ Qp,
                                u16* __restrict__ Kout, u16* __restrict__ VTout) {
  const int K = 1280, N = 1280;
  const size_t WSZ = (size_t)1280 * 1280;
  __shared__ u16 As[128 * 32];
  __shared__ u16 Bs[128 * 32];

  int tid = threadIdx.x;
  int wid = tid >> 6, lane = tid & 63;
  int nb = blockIdx.x, mb = blockIdx.y, z = blockIdx.z;
  int m0 = mb * 128, n0 = nb * 128;
  bool first = ((m0 & 2047) < 1024);   // first half of sequence -> attn weights

  const u16* B;
  switch (z) {
    case 0:  B = Wt + 0 * WSZ; break;
    case 1:  B = Wt + 4 * WSZ; break;
    case 2:  B = first ? Wt + 1 * WSZ : Wt + 5 * WSZ; break;
    default: B = first ? Wt + 2 * WSZ : Wt + 6 * WSZ; break;
  }

  f32x4 zero = {0.f, 0.f, 0.f, 0.f};
  f32x4 acc[4][4];
#pragma unroll
  for (int i = 0; i < 4; i++)
#pragma unroll
    for (int j = 0; j < 4; j++) acc[i][j] = zero;

  int wr = wid >> 1, wc = wid & 1;

  for (int kk = 0; kk < 40; kk++) {
    int k0 = kk * 32;
#pragma unroll
    for (int i = 0; i < 2; i++) {
      int slot = i * 256 + tid;
      int row = slot >> 2, seg = slot & 3;
      async_copy16(A + (size_t)(m0 + row) * K + k0 + seg * 8, As + (size_t)(i * 256 + wid * 64) * 8);
      async_copy16(B + (size_t)(n0 + row) * K + k0 + seg * 8, Bs + (size_t)(i * 256 + wid * 64) * 8);
    }
    asm volatile("s_waitcnt vmcnt(0)" ::: "memory");
    __syncthreads();

    u16x8 af[4], bfr[4];
#pragma unroll
    for (int mi = 0; mi < 4; mi++)
      af[mi] = *(const u16x8*)(As + (wr * 64 + mi * 16 + (lane & 15)) * 32 + (lane >> 4) * 8);
#pragma unroll
    for (int ni = 0; ni < 4; ni++)
      bfr[ni] = *(const u16x8*)(Bs + (wc * 64 + ni * 16 + (lane & 15)) * 32 + (lane >> 4) * 8);
#pragma unroll
    for (int mi = 0; mi < 4; mi++)
#pragma unroll
      for (int ni = 0; ni < 4; ni++)
        acc[mi][ni] = mfma16(af[mi], bfr[ni], acc[mi][ni]);
    __syncthreads();
  }

  if (z == 3) {
    // V^T layout: [b*8+h][c_in (160)][s (2048)]
#pragma unroll
    for (int mi = 0; mi < 4; mi++)
#pragma unroll
      for (int ni = 0; ni < 4; ni++) {
        int row0 = m0 + wr * 64 + mi * 16 + ((lane >> 4) << 2);  // 4 consecutive tokens
        int col = n0 + wc * 64 + ni * 16 + (lane & 15);
        int b = row0 >> 11, s = row0 & 2047;
        int h = col / 160, c_in = col - h * 160;
        u16x4 v = {f2b(acc[mi][ni][0]), f2b(acc[mi][ni][1]),
                   f2b(acc[mi][ni][2]), f2b(acc[mi][ni][3])};
        *(u16x4*)(VTout + ((size_t)(b * 8 + h) * 160 + c_in) * 2048 + s) = v;
      }
  } else {
    u16* Cb = (z == 0) ? Qa : (z == 1) ? Qp : Kout;
#pragma unroll
    for (int mi = 0; mi < 4; mi++)
#pragma unroll
      for (int ni = 0; ni < 4; ni++)
#pragma unroll
        for (int r = 0; r < 4; r++) {
          int row = m0 + wr * 64 + mi * 16 + ((lane >> 4) << 2) + r;
          int col = n0 + wc * 64 + ni * 16 + (lane & 15);
          Cb[(size_t)row * N + col] = f2b(acc[mi][ni][r]);
        }
  }
}

// ---------- 3b. Q blend: Qa = (w*Qa + (1-w)*Qp) * qscale ----------
__global__ void qblend_kernel(u16* __restrict__ Qa, const u16* __restrict__ Qp,
                              const float* __restrict__ wgate, float qscale) {
  int idx = blockIdx.x * 256 + threadIdx.x;   // vec8 index, 655360 total
  int token = idx / 160;                       // 160 vec8 per token row
  float w = wgate[token];
  u16x8 qa = *(const u16x8*)(Qa + (size_t)idx * 8);
  u16x8 qp = *(const u16x8*)(Qp + (size_t)idx * 8);
  u16x8 o;
#pragma unroll
  for (int j = 0; j < 8; j++)
    o[j] = f2b((w * b2f(qa[j]) + (1.f - w) * b2f(qp[j])) * qscale);
  *(u16x8*)(Qa + (size_t)idx * 8) = o;
}

// ---------- 4. flash attention (kv-split, pipelined staging) ----------
// LDS 47104 B (< 48 KiB; 8-KiB-granule theory -> 3 blocks/CU = 12 waves).
// Pipelined: K(t+1) issued after QK consumes Ks (overlaps softmax+PV);
// V(t+1) issued after PV consumes Vts (overlaps next QK). Counted vmcnt only
// (never 0 in steady state); raw s_barrier (NOT __syncthreads which drains).
// Per-wave load counts equalized: 6 K-instr (waves 1-3 dup last chunk) + 5 V.
// P buffer halved: [4][16][40] written/read per kt2 phase (wave-private;
// DS ops are in-order per wave so WAR on overwrite is safe).
template <int SPLIT>
__launch_bounds__(256)
__global__ void flash_kernel(const u16* __restrict__ Q, const u16* __restrict__ Kg,
                             const u16* __restrict__ VTg, u16* __restrict__ O,
                             u16* __restrict__ Opart, float* __restrict__ MLbuf) {
  const int C = 1280;
  int bid = blockIdx.x;
  int qb = bid & 31, h = (bid >> 5) & 7, b = bid >> 8;
  int sp = (SPLIT > 1) ? (int)blockIdx.y : 0;
  int tid = threadIdx.x, wid = tid >> 6, lane = tid & 63;

  // tile range for this split (SPLIT=3: 11/11/10 tiles)
  int t0, NT;
  if (SPLIT == 3) { t0 = sp * 11; NT = (sp < 2) ? 11 : 10; }
  else if (SPLIT == 1) { t0 = 0; NT = 32; }
  else { t0 = sp * (32 / SPLIT); NT = 32 / SPLIT; }

  const size_t baseQ = ((size_t)(b * 2048 + qb * 64)) * C + h * 160;
  const size_t baseK = ((size_t)(b * 2048)) * C + h * 160;
  const size_t baseVT = (size_t)(b * 8 + h) * 160 * 2048;

  __shared__ u16 Ks[64 * 168];     // 21504 B
  __shared__ u16 Vts[160 * 64];    // 20480 B, chunk-swizzled
  __shared__ u16 Psh[4 * 16 * 40]; // 5120 B (half-P, per-kt2 phase)

  // ---- hoisted staging addresses (div-by-21 chains out of the loop) ----
  const u16* kbase = Kg + baseK + (size_t)(t0 * 64) * C;  // += 64*C per tile
  const u16* vbase = VTg + baseVT + t0 * 64;               // += 64 per tile
  unsigned koff[6], kld[6];
#pragma unroll
  for (int j = 0; j < 6; j++) {
    int i = wid + 4 * j;
    if (i > 20) i = wid + 16;          // waves 1-3: duplicate last chunk (benign)
    int gc = i * 64 + lane;
    int r = gc / 21, ch = gc - r * 21;
    int chs = ch < 20 ? ch : 19;
    koff[j] = (unsigned)(r * C + chs * 8);
    kld[j] = (unsigned)(i * 512);
  }
  unsigned voff[5], vld[5];
#pragma unroll
  for (int j = 0; j < 5; j++) {
    int i = wid + 4 * j;
    int gc = i * 64 + lane;
    int c = gc >> 3, jj = gc & 7;
    voff[j] = (unsigned)(c * 2048 + ((jj ^ (c & 7)) << 3));
    vld[j] = (unsigned)(i * 512);
  }

#define STAGE_K()                                   \
  do {                                              \
    _Pragma("unroll") for (int j = 0; j < 6; j++)   \
        async_copy16(kbase + koff[j], Ks + kld[j]); \
  } while (0)
#define STAGE_V()                                    \
  do {                                               \
    _Pragma("unroll") for (int j = 0; j < 5; j++)    \
        async_copy16(vbase + voff[j], Vts + vld[j]); \
  } while (0)

  // Q fragments (issued first: oldest vmcnt entries, drained by first wait)
  u16x8 qf[5];
  {
    int row = wid * 16 + (lane & 15);
    const u16* qrow = Q + baseQ + (size_t)row * C;
#pragma unroll
    for (int ks = 0; ks < 5; ks++)
      qf[ks] = *(const u16x8*)(qrow + ks * 32 + (lane >> 4) * 8);
  }

  f32x4 zero = {0.f, 0.f, 0.f, 0.f};
  f32x4 oacc[10];
#pragma unroll
  for (int i = 0; i < 10; i++) oacc[i] = zero;
  float mrow[4], lrow[4];
#pragma unroll
  for (int r = 0; r < 4; r++) { mrow[r] = -1e30f; lrow[r] = 0.f; }

  // prologue: stage tile 0
  STAGE_K();
  STAGE_V();

  for (int kti = 0; kti < NT; kti++) {
    bool last = (kti == NT - 1);
    // K(t) ready; V(t)'s 5 loads may remain in flight
    asm volatile("s_waitcnt vmcnt(5)" ::: "memory");
    fence_barrier();

    // scores: 16 q-rows x 64 kv (log2 domain; scale folded into Q)
    f32x4 sc[4];
#pragma unroll
    for (int ct = 0; ct < 4; ct++) {
      f32x4 a = zero;
#pragma unroll
      for (int ks = 0; ks < 5; ks++) {
        u16x8 kf = *(const u16x8*)(&Ks[(ct * 16 + (lane & 15)) * 168 + ks * 32 + (lane >> 4) * 8]);
        a = mfma16(qf[ks], kf, a);
      }
      sc[ct] = a;
    }

    fence_barrier();                    // all waves done reading Ks(t)
    if (!last) { kbase += 64 * C; STAGE_K(); }   // K(t+1) overlaps softmax+PV

    // online softmax (defer-max, THR=8 in log2 units); lrow per-lane partial
    float mx[4];
#pragma unroll
    for (int r = 0; r < 4; r++) {
      float m = fmaxf(fmaxf(sc[0][r], sc[1][r]), fmaxf(sc[2][r], sc[3][r]));
#pragma unroll
      for (int off = 1; off < 16; off <<= 1) m = fmaxf(m, __shfl_xor(m, off));
      mx[r] = m;
    }
    bool need = (mx[0] > mrow[0] + 8.f) || (mx[1] > mrow[1] + 8.f) ||
                (mx[2] > mrow[2] + 8.f) || (mx[3] > mrow[3] + 8.f);
    if (__any(need)) {
#pragma unroll
      for (int r = 0; r < 4; r++) {
        float mnew = fmaxf(mrow[r], mx[r]);
        float alpha = EXP2F(mrow[r] - mnew);
        mrow[r] = mnew;
        float rs = 0.f;
#pragma unroll
        for (int ct = 0; ct < 4; ct++) {
          float p = EXP2F(sc[ct][r] - mnew);
          sc[ct][r] = p;
          rs += p;
        }
        lrow[r] = lrow[r] * alpha + rs;
#pragma unroll
        for (int ci = 0; ci < 10; ci++) oacc[ci][r] *= alpha;
      }
    } else {
#pragma unroll
      for (int r = 0; r < 4; r++) {
        float rs = 0.f;
#pragma unroll
        for (int ct = 0; ct < 4; ct++) {
          float p = EXP2F(sc[ct][r] - mrow[r]);
          sc[ct][r] = p;
          rs += p;
        }
        lrow[r] += rs;
      }
    }

    // V(t) ready (leave the 6 K(t+1) loads in flight)
    if (!last) { asm volatile("s_waitcnt vmcnt(6)" ::: "memory"); }
    else       { asm volatile("s_waitcnt vmcnt(0)" ::: "memory"); }
    fence_barrier();

    // PV in two kt2 phases through the half-P buffer (wave-private)
#pragma unroll
    for (int kt2 = 0; kt2 < 2; kt2++) {
#pragma unroll
      for (int c2 = 0; c2 < 2; c2++) {
        int ct = kt2 * 2 + c2;
#pragma unroll
        for (int r = 0; r < 4; r++)
          Psh[wid * 640 + ((((lane >> 4) << 2) + r) * 40) + c2 * 16 + (lane & 15)] =
              f2b(sc[ct][r]);
      }
      u16x8 pf = *(const u16x8*)(&Psh[wid * 640 + (lane & 15) * 40 + (lane >> 4) * 8]);
#pragma unroll
      for (int ci = 0; ci < 10; ci++) {
        int c = ci * 16 + (lane & 15);
        int jl = kt2 * 4 + (lane >> 4);
        u16x8 vf = *(const u16x8*)(&Vts[c * 64 + ((jl ^ (c & 7)) << 3)]);
        oacc[ci] = mfma16(pf, vf, oacc[ci]);
      }
    }

    fence_barrier();                    // all waves done reading Vts(t)
    if (!last) { vbase += 64; STAGE_V(); }       // V(t+1) overlaps next QK
  }
#undef STAGE_K
#undef STAGE_V

  // single deferred l reduce across the 16-lane row group
#pragma unroll
  for (int r = 0; r < 4; r++)
#pragma unroll
    for (int off = 1; off < 16; off <<= 1) lrow[r] += __shfl_xor(lrow[r], off);

  int row0 = qb * 64 + wid * 16 + ((lane >> 4) << 2);
  if constexpr (SPLIT > 1) {
    // l-normalized bf16 partials (values O(1), bf16-safe) + (m,l) per row/head
    float linv[4];
#pragma unroll
    for (int r = 0; r < 4; r++) linv[r] = 1.f / lrow[r];
    size_t g0 = (size_t)sp * 4096 + (size_t)b * 2048 + row0;
#pragma unroll
    for (int ci = 0; ci < 10; ci++) {
      int col = h * 160 + ci * 16 + (lane & 15);
#pragma unroll
      for (int r = 0; r < 4; r++)
        Opart[(g0 + r) * 1280 + col] = f2b(oacc[ci][r] * linv[r]);
    }
    if ((lane & 15) == 0) {
#pragma unroll
      for (int r = 0; r < 4; r++) {
        size_t mi = ((g0 + r) * 8 + h) * 2;
        MLbuf[mi] = mrow[r];
        MLbuf[mi + 1] = lrow[r];
      }
    }
  } else {
#pragma unroll
    for (int ci = 0; ci < 10; ci++) {
      int col = h * 160 + ci * 16 + (lane & 15);
#pragma unroll
      for (int r = 0; r < 4; r++) {
        float v = oacc[ci][r] / lrow[r];
        O[((size_t)(b * 2048) + row0 + r) * C + col] = f2b(v);
      }
    }
  }
}

// ---------- 4b. combine the three kv-split parts (vec8) ----------
// O = sum_p v_p*a_p*l_p / sum_p a_p*l_p, a_p = 2^(m_p - max m)
__global__ void combine_kernel(const u16* __restrict__ Opart, const float* __restrict__ MLbuf,
                               u16* __restrict__ O) {
  int idx = blockIdx.x * 256 + threadIdx.x;   // vec8 index, 655360 total
  int token = idx / 160;
  int h = (idx - token * 160) / 20;
  size_t i0 = ((size_t)token * 8 + h) * 2;
  const size_t MLP = (size_t)4096 * 16;       // floats per part
  float m0 = MLbuf[i0], l0 = MLbuf[i0 + 1];
  float m1 = MLbuf[i0 + MLP], l1 = MLbuf[i0 + MLP + 1];
  float m2 = MLbuf[i0 + 2 * MLP], l2 = MLbuf[i0 + 2 * MLP + 1];
  float m = fmaxf(fmaxf(m0, m1), m2);
  float w0 = EXP2F(m0 - m) * l0, w1 = EXP2F(m1 - m) * l1, w2 = EXP2F(m2 - m) * l2;
  float inv = 1.f / (w0 + w1 + w2);
  w0 *= inv; w1 *= inv; w2 *= inv;
  const size_t OPP = (size_t)655360;          // vec8 per part
  u16x8 a = *(const u16x8*)(Opart + (size_t)idx * 8);
  u16x8 c = *(const u16x8*)(Opart + (OPP + idx) * 8);
  u16x8 d = *(const u16x8*)(Opart + (2 * OPP + idx) * 8);
  u16x8 o;
#pragma unroll
  for (int j = 0; j < 8; j++)
    o[j] = f2b(b2f(a[j]) * w0 + b2f(c[j]) * w1 + b2f(d[j]) * w2);
  *(u16x8*)(O + (size_t)idx * 8) = o;
}

// ---------- 5. out-proj GEMM: C = A@B0 + bias + resid -> fp32 ----------
__launch_bounds__(256)
__global__ void gemm_out_kernel(const u16* __restrict__ A, const u16* __restrict__ Bt,
                                float* __restrict__ Cf, const float* __restrict__ bias,
                                const float* __restrict__ resid) {
  const int K = 1280, N = 1280;
  __shared__ u16 As[128 * 32];
  __shared__ u16 Bs[128 * 32];

  int tid = threadIdx.x;
  int wid = tid >> 6, lane = tid & 63;
  int nb = blockIdx.x, mb = blockIdx.y;
  int m0 = mb * 128, n0 = nb * 128;

  f32x4 zero = {0.f, 0.f, 0.f, 0.f};
  f32x4 acc[4][4];
#pragma unroll
  for (int i = 0; i < 4; i++)
#pragma unroll
    for (int j = 0; j < 4; j++) acc[i][j] = zero;

  int wr = wid >> 1, wc = wid & 1;

  for (int kk = 0; kk < 40; kk++) {
    int k0 = kk * 32;
#pragma unroll
    for (int i = 0; i < 2; i++) {
      int slot = i * 256 + tid;
      int row = slot >> 2, seg = slot & 3;
      async_copy16(A + (size_t)(m0 + row) * K + k0 + seg * 8, As + (size_t)(i * 256 + wid * 64) * 8);
      async_copy16(Bt + (size_t)(n0 + row) * K + k0 + seg * 8, Bs + (size_t)(i * 256 + wid * 64) * 8);
    }
    asm volatile("s_waitcnt vmcnt(0)" ::: "memory");
    __syncthreads();

    u16x8 af[4], bfr[4];
#pragma unroll
    for (int mi = 0; mi < 4; mi++)
      af[mi] = *(const u16x8*)(As + (wr * 64 + mi * 16 + (lane & 15)) * 32 + (lane >> 4) * 8);
#pragma unroll
    for (int ni = 0; ni < 4; ni++)
      bfr[ni] = *(const u16x8*)(Bs + (wc * 64 + ni * 16 + (lane & 15)) * 32 + (lane >> 4) * 8);
#pragma unroll
    for (int mi = 0; mi < 4; mi++)
#pragma unroll
      for (int ni = 0; ni < 4; ni++)
        acc[mi][ni] = mfma16(af[mi], bfr[ni], acc[mi][ni]);
    __syncthreads();
  }

#pragma unroll
  for (int mi = 0; mi < 4; mi++)
#pragma unroll
    for (int ni = 0; ni < 4; ni++)
#pragma unroll
      for (int r = 0; r < 4; r++) {
        int row = m0 + wr * 64 + mi * 16 + ((lane >> 4) << 2) + r;
        int col = n0 + wc * 64 + ni * 16 + (lane & 15);
        Cf[(size_t)row * N + col] = acc[mi][ni][r] + bias[col] + resid[(size_t)row * N + col];
      }
}

// ---------- launch ----------
extern "C" void kernel_launch(void* const* d_in, const int* in_sizes, int n_in,
                              void* d_out, int out_size, void* d_ws, size_t ws_size,
                              hipStream_t stream) {
  const float* hs      = (const float*)d_in[0];
  const float* mask    = (const float*)d_in[1];
  const float* attn_wq = (const float*)d_in[2];
  const float* attn_wk = (const float*)d_in[3];
  const float* attn_wv = (const float*)d_in[4];
  const float* out_w   = (const float*)d_in[5];
  const float* out_b   = (const float*)d_in[6];
  const float* proc_wq = (const float*)d_in[7];
  const float* proc_wk = (const float*)d_in[8];
  const float* proc_wv = (const float*)d_in[9];
  const float* ww      = (const float*)d_in[10];
  const float* wb      = (const float*)d_in[11];
  float* out = (float*)d_out;

  char* ws = (char*)d_ws;
  const size_t TOK = (size_t)4096 * 1280;     // tokens x channels
  u16* hsb = (u16*)(ws);
  u16* Qb  = (u16*)(ws + 2 * TOK);
  u16* Kb  = (u16*)(ws + 4 * TOK);
  u16* VTb = (u16*)(ws + 6 * TOK);            // V^T [16][160][2048]
  u16* AOb = (u16*)(ws + 8 * TOK);            // doubles as Qp temp before flash
  u16* Wt  = (u16*)(ws + 10 * TOK);           // 7 x 1280x1280 bf16
  float* wgate = (float*)(ws + 10 * TOK + (size_t)7 * 1280 * 1280 * 2);
  char* extra = ws + 10 * TOK + (size_t)7 * 1280 * 1280 * 2 + 16384;
  u16* Opart = (u16*)extra;                                     // [3][4096][1280] bf16
  float* MLbuf = (float*)(extra + (size_t)3 * 4096 * 1280 * 2); // [3][4096][8]{m,l}
  size_t need = (size_t)(extra - ws) + (size_t)3 * 4096 * 1280 * 2 + (size_t)3 * 4096 * 8 * 8;

  prep_kernel<<<4096, 256, 0, stream>>>(hs, mask, ww, wb, hsb, wgate);
  wtrans_kernel<<<dim3(40, 40, 7), 256, 0, stream>>>(attn_wq, attn_wk, attn_wv, out_w,
                                                     proc_wq, proc_wk, proc_wv, Wt);
  const size_t WSZ = (size_t)1280 * 1280;
  // merged Qa/Qp/K/V GEMM: 1280 uniform blocks
  gemm_qkv_kernel<<<dim3(10, 32, 4), 256, 0, stream>>>(hsb, Wt, Qb, AOb, Kb, VTb);
  // 1/sqrt(160) * log2(e): scores land in log2 domain
  const float qscale = 0.11405505533858971f;
  qblend_kernel<<<2560, 256, 0, stream>>>(Qb, AOb, wgate, qscale);

  if (ws_size >= need) {
    flash_kernel<3><<<dim3(512, 3), 256, 0, stream>>>(Qb, Kb, VTb, nullptr, Opart, MLbuf);
    combine_kernel<<<2560, 256, 0, stream>>>(Opart, MLbuf, AOb);
  } else {
    flash_kernel<1><<<dim3(512, 1), 256, 0, stream>>>(Qb, Kb, VTb, AOb, nullptr, nullptr);
  }
  gemm_out_kernel<<<dim3(10, 32), 256, 0, stream>>>(AOb, Wt + 3 * WSZ, out, out_b, hs);
}

// Round 4
// 240.416 us; speedup vs baseline: 1.7821x; 1.0437x over previous
//
#include <hip/hip_runtime.h>

typedef unsigned short u16;
typedef u16 u16x4 __attribute__((ext_vector_type(4)));
typedef u16 u16x8 __attribute__((ext_vector_type(8)));
typedef __bf16 bf16x8 __attribute__((ext_vector_type(8)));
typedef float f32x4 __attribute__((ext_vector_type(4)));
typedef unsigned u32x4 __attribute__((ext_vector_type(4)));

#define DEVI __device__ __forceinline__

#if __has_builtin(__builtin_amdgcn_exp2f)
#define EXP2F __builtin_amdgcn_exp2f
#else
#define EXP2F exp2f
#endif

// ---------- helpers ----------
DEVI u16 f2b(float f) {  // fp32 -> bf16 RNE
  unsigned u = __builtin_bit_cast(unsigned, f);
  u += 0x7fffu + ((u >> 16) & 1u);
  return (u16)(u >> 16);
}

DEVI float b2f(u16 v) { return __builtin_bit_cast(float, (unsigned)v << 16); }

DEVI unsigned cvtpk_bf16(float lo, float hi) {  // dword = {bf16(lo), bf16(hi)<<16}
  unsigned r;
  asm("v_cvt_pk_bf16_f32 %0, %1, %2" : "=v"(r) : "v"(lo), "v"(hi));
  return r;
}

DEVI f32x4 mfma16(u16x8 a, u16x8 b, f32x4 c) {
  return __builtin_amdgcn_mfma_f32_16x16x32_bf16(
      __builtin_bit_cast(bf16x8, a), __builtin_bit_cast(bf16x8, b), c, 0, 0, 0);
}

DEVI void async_copy16(const u16* g, u16* l) {
  __builtin_amdgcn_global_load_lds(
      (__attribute__((address_space(1))) unsigned int*)(g),
      (__attribute__((address_space(3))) unsigned int*)(l), 16, 0, 0);
}

// raw barrier with compiler memory fences on both sides (NOT __syncthreads:
// that emits s_waitcnt vmcnt(0) and would kill the counted-vmcnt pipeline)
DEVI void fence_barrier() {
  asm volatile("" ::: "memory");
  __builtin_amdgcn_s_barrier();
  asm volatile("" ::: "memory");
}

// ---------- 1. hs->bf16 + gate ----------
__global__ void prep_kernel(const float* __restrict__ hs, const float* __restrict__ mask,
                            const float* __restrict__ ww, const float* __restrict__ wb,
                            u16* __restrict__ hsb, float* __restrict__ wgate) {
  int token = blockIdx.x;            // 0..4095
  int tid = threadIdx.x;             // 256
  const float* row = hs + (size_t)token * 1280;
  u16* orow = hsb + (size_t)token * 1280;
  float acc = 0.f;
#pragma unroll
  for (int i = 0; i < 5; i++) {
    int c = i * 256 + tid;
    float v = row[c];
    orow[c] = f2b(v);
    acc += v * ww[c];
  }
#pragma unroll
  for (int off = 1; off < 64; off <<= 1) acc += __shfl_xor(acc, off);
  __shared__ float partial[4];
  int wid = tid >> 6;
  if ((tid & 63) == 0) partial[wid] = acc;
  __syncthreads();
  if (tid == 0) {
    float tot = partial[0] + partial[1] + partial[2] + partial[3];
    int b = token >> 11, t = token & 2047;
    int s = t & 1023;
    float mv = mask[b * 65536 + ((s >> 5) * 8) * 256 + (s & 31) * 8];
    float z = tot + mv * ww[1280] + wb[0];
    wgate[token] = 1.f / (1.f + __expf(-z));
  }
}

// ---------- 2. weight transpose + bf16 ----------
__global__ void wtrans_kernel(const float* w0, const float* w1, const float* w2,
                              const float* w3, const float* w4, const float* w5,
                              const float* w6, u16* __restrict__ out) {
  const float* src;
  switch (blockIdx.z) {
    case 0: src = w0; break; case 1: src = w1; break; case 2: src = w2; break;
    case 3: src = w3; break; case 4: src = w4; break; case 5: src = w5; break;
    default: src = w6; break;
  }
  u16* dst = out + (size_t)blockIdx.z * 1280 * 1280;
  __shared__ float tile[32][33];
  int tx = threadIdx.x & 31, ty = threadIdx.x >> 5;   // 32x8
  int k0 = blockIdx.x * 32, n0 = blockIdx.y * 32;
#pragma unroll
  for (int r = 0; r < 4; r++)
    tile[ty + r * 8][tx] = src[(size_t)(k0 + ty + r * 8) * 1280 + n0 + tx];
  __syncthreads();
#pragma unroll
  for (int r = 0; r < 4; r++)
    dst[(size_t)(n0 + ty + r * 8) * 1280 + k0 + tx] = f2b(tile[tx][ty + r * 8]);
}

// ---------- 3. merged QKV GEMM: 4 uniform 128x128 tile jobs per (nb,mb) ----------
// z=0: A@attn_wq -> Qa ; z=1: A@proc_wq -> Qp ; z=2: K (half-selected) -> Kb row-major
// z=3: V (half-selected) -> VTb transposed [b*8+h][160][2048]
__launch_bounds__(256)
__global__ void gemm_qkv_kernel(const u16* __restrict__ A, const u16* __restrict__ Wt,
                                u16* __restrict__ Qa, u16* __restrict__ Qp,
                                u16* __restrict__ Kout, u16* __restrict__ VTout) {
  const int K = 1280, N = 1280;
  const size_t WSZ = (size_t)1280 * 1280;
  __shared__ u16 As[128 * 32];
  __shared__ u16 Bs[128 * 32];

  int tid = threadIdx.x;
  int wid = tid >> 6, lane = tid & 63;
  int nb = blockIdx.x, mb = blockIdx.y, z = blockIdx.z;
  int m0 = mb * 128, n0 = nb * 128;
  bool first = ((m0 & 2047) < 1024);   // first half of sequence -> attn weights

  const u16* B;
  switch (z) {
    case 0:  B = Wt + 0 * WSZ; break;
    case 1:  B = Wt + 4 * WSZ; break;
    case 2:  B = first ? Wt + 1 * WSZ : Wt + 5 * WSZ; break;
    default: B = first ? Wt + 2 * WSZ : Wt + 6 * WSZ; break;
  }

  f32x4 zero = {0.f, 0.f, 0.f, 0.f};
  f32x4 acc[4][4];
#pragma unroll
  for (int i = 0; i < 4; i++)
#pragma unroll
    for (int j = 0; j < 4; j++) acc[i][j] = zero;

  int wr = wid >> 1, wc = wid & 1;

  for (int kk = 0; kk < 40; kk++) {
    int k0 = kk * 32;
#pragma unroll
    for (int i = 0; i < 2; i++) {
      int slot = i * 256 + tid;
      int row = slot >> 2, seg = slot & 3;
      async_copy16(A + (size_t)(m0 + row) * K + k0 + seg * 8, As + (size_t)(i * 256 + wid * 64) * 8);
      async_copy16(B + (size_t)(n0 + row) * K + k0 + seg * 8, Bs + (size_t)(i * 256 + wid * 64) * 8);
    }
    asm volatile("s_waitcnt vmcnt(0)" ::: "memory");
    __syncthreads();

    u16x8 af[4], bfr[4];
#pragma unroll
    for (int mi = 0; mi < 4; mi++)
      af[mi] = *(const u16x8*)(As + (wr * 64 + mi * 16 + (lane & 15)) * 32 + (lane >> 4) * 8);
#pragma unroll
    for (int ni = 0; ni < 4; ni++)
      bfr[ni] = *(const u16x8*)(Bs + (wc * 64 + ni * 16 + (lane & 15)) * 32 + (lane >> 4) * 8);
#pragma unroll
    for (int mi = 0; mi < 4; mi++)
#pragma unroll
      for (int ni = 0; ni < 4; ni++)
        acc[mi][ni] = mfma16(af[mi], bfr[ni], acc[mi][ni]);
    __syncthreads();
  }

  if (z == 3) {
    // V^T layout: [b*8+h][c_in (160)][s (2048)]
#pragma unroll
    for (int mi = 0; mi < 4; mi++)
#pragma unroll
      for (int ni = 0; ni < 4; ni++) {
        int row0 = m0 + wr * 64 + mi * 16 + ((lane >> 4) << 2);  // 4 consecutive tokens
        int col = n0 + wc * 64 + ni * 16 + (lane & 15);
        int b = row0 >> 11, s = row0 & 2047;
        int h = col / 160, c_in = col - h * 160;
        u16x4 v = {f2b(acc[mi][ni][0]), f2b(acc[mi][ni][1]),
                   f2b(acc[mi][ni][2]), f2b(acc[mi][ni][3])};
        *(u16x4*)(VTout + ((size_t)(b * 8 + h) * 160 + c_in) * 2048 + s) = v;
      }
  } else {
    u16* Cb = (z == 0) ? Qa : (z == 1) ? Qp : Kout;
#pragma unroll
    for (int mi = 0; mi < 4; mi++)
#pragma unroll
      for (int ni = 0; ni < 4; ni++)
#pragma unroll
        for (int r = 0; r < 4; r++) {
          int row = m0 + wr * 64 + mi * 16 + ((lane >> 4) << 2) + r;
          int col = n0 + wc * 64 + ni * 16 + (lane & 15);
          Cb[(size_t)row * N + col] = f2b(acc[mi][ni][r]);
        }
  }
}

// ---------- 3b. Q blend: Qa = (w*Qa + (1-w)*Qp) * qscale ----------
__global__ void qblend_kernel(u16* __restrict__ Qa, const u16* __restrict__ Qp,
                              const float* __restrict__ wgate, float qscale) {
  int idx = blockIdx.x * 256 + threadIdx.x;   // vec8 index, 655360 total
  int token = idx / 160;                       // 160 vec8 per token row
  float w = wgate[token];
  u16x8 qa = *(const u16x8*)(Qa + (size_t)idx * 8);
  u16x8 qp = *(const u16x8*)(Qp + (size_t)idx * 8);
  u16x8 o;
#pragma unroll
  for (int j = 0; j < 8; j++)
    o[j] = f2b((w * b2f(qa[j]) + (1.f - w) * b2f(qp[j])) * qscale);
  *(u16x8*)(Qa + (size_t)idx * 8) = o;
}

// ---------- 4. flash attention (kv-split, swapped-operand, P-in-register) ----------
// Swapped MFMA: sc = mfma(K, Q) and oacc = mfma(V, P). A/B fragment symmetry
// means K/Q/V LDS reads are IDENTICAL to the unswapped version; but the C
// layout becomes q = lane&15 for everything: softmax state is lane-scalar,
// alpha-rescale needs no shuffles, and the P transpose for PV's B-fragment is
// a pure lane permutation: cvt_pk_bf16 + ds_bpermute (no Psh LDS buffer).
// LDS 41984 B: under the (new) 128-KiB-pool occupancy model -> 3 blocks/CU.
// Pipelined staging with counted vmcnt (K: 6 instr/wave, V: 5 instr/wave).
template <int SPLIT>
__launch_bounds__(256)
__global__ void flash_kernel(const u16* __restrict__ Q, const u16* __restrict__ Kg,
                             const u16* __restrict__ VTg, u16* __restrict__ O,
                             u16* __restrict__ Opart, float* __restrict__ MLbuf) {
  const int C = 1280;
  int bid = blockIdx.x;
  int qb = bid & 31, h = (bid >> 5) & 7, b = bid >> 8;
  int sp = (SPLIT > 1) ? (int)blockIdx.y : 0;
  int tid = threadIdx.x, wid = tid >> 6, lane = tid & 63;

  // tile range for this split (SPLIT=3: 11/11/10 tiles)
  int t0, NT;
  if (SPLIT == 3) { t0 = sp * 11; NT = (sp < 2) ? 11 : 10; }
  else if (SPLIT == 1) { t0 = 0; NT = 32; }
  else { t0 = sp * (32 / SPLIT); NT = 32 / SPLIT; }

  const size_t baseQ = ((size_t)(b * 2048 + qb * 64)) * C + h * 160;
  const size_t baseK = ((size_t)(b * 2048)) * C + h * 160;
  const size_t baseVT = (size_t)(b * 8 + h) * 160 * 2048;

  __shared__ u16 Ks[64 * 168];     // 21504 B
  __shared__ u16 Vts[160 * 64];    // 20480 B, chunk-swizzled  => total 41984 B

  // ---- hoisted staging addresses ----
  const u16* kbase = Kg + baseK + (size_t)(t0 * 64) * C;  // += 64*C per tile
  const u16* vbase = VTg + baseVT + t0 * 64;               // += 64 per tile
  unsigned koff[6];
#pragma unroll
  for (int j = 0; j < 6; j++) {
    int i = wid + 4 * j;
    if (i > 20) i = wid + 16;          // waves 1-3: duplicate last chunk (benign)
    int gc = i * 64 + lane;
    int r = gc / 21, ch = gc - r * 21;
    int chs = ch < 20 ? ch : 19;
    koff[j] = (unsigned)(r * C + chs * 8);
  }
  unsigned voff[5];
#pragma unroll
  for (int j = 0; j < 5; j++) {
    int i = wid + 4 * j;
    int gc = i * 64 + lane;
    int c = gc >> 3, jj = gc & 7;
    voff[j] = (unsigned)(c * 2048 + ((jj ^ (c & 7)) << 3));
  }

#define STAGE_K()                                       \
  do {                                                  \
    _Pragma("unroll") for (int j = 0; j < 6; j++) {     \
      int i = wid + 4 * j;                              \
      if (i > 20) i = wid + 16;                         \
      async_copy16(kbase + koff[j], Ks + i * 512);      \
    }                                                   \
  } while (0)
#define STAGE_V()                                               \
  do {                                                          \
    _Pragma("unroll") for (int j = 0; j < 5; j++)               \
        async_copy16(vbase + voff[j], Vts + (wid + 4 * j) * 512); \
  } while (0)

  // P-transpose lane constants: target lane l pulls P(q=l&15, kv) from source
  // lane s = (l&15) + 16*(((l>>4)*2 + g)&3), g = j>>2; register half by l>=32.
  const int addr0 = ((lane & 15) + 16 * (((lane >> 4) * 2 + 0) & 3)) << 2;
  const int addr1 = ((lane & 15) + 16 * (((lane >> 4) * 2 + 1) & 3)) << 2;
  const bool hihalf = (lane >= 32);

  // Q fragments
  u16x8 qf[5];
  {
    int row = wid * 16 + (lane & 15);
    const u16* qrow = Q + baseQ + (size_t)row * C;
#pragma unroll
    for (int ks = 0; ks < 5; ks++)
      qf[ks] = *(const u16x8*)(qrow + ks * 32 + (lane >> 4) * 8);
  }

  f32x4 zero = {0.f, 0.f, 0.f, 0.f};
  f32x4 oacc[10];
#pragma unroll
  for (int i = 0; i < 10; i++) oacc[i] = zero;
  float mrow = -1e30f, lrow = 0.f;   // lane-scalar: this lane's q = lane&15

  // prologue: stage tile 0
  STAGE_K();
  STAGE_V();

  for (int kti = 0; kti < NT; kti++) {
    bool last = (kti == NT - 1);
    // K(t) ready; V(t)'s 5 loads may remain in flight
    asm volatile("s_waitcnt vmcnt(5)" ::: "memory");
    fence_barrier();

    // scores (swapped): sc[ct] col = q = lane&15, row = kv = ct*16+(lane>>4)*4+r
    f32x4 sc[4];
#pragma unroll
    for (int ct = 0; ct < 4; ct++) {
      f32x4 a = zero;
#pragma unroll
      for (int ks = 0; ks < 5; ks++) {
        u16x8 kf = *(const u16x8*)(&Ks[(ct * 16 + (lane & 15)) * 168 + ks * 32 + (lane >> 4) * 8]);
        a = mfma16(kf, qf[ks], a);
      }
      sc[ct] = a;
    }

    fence_barrier();                    // all waves done reading Ks(t)
    if (!last) { kbase += 64 * C; STAGE_K(); }   // K(t+1) overlaps softmax+PV

    // ---- softmax, all state lane-scalar (q = lane&15) ----
    float m = sc[0][0];
#pragma unroll
    for (int ct = 0; ct < 4; ct++)
#pragma unroll
      for (int r = 0; r < 4; r++) m = fmaxf(m, sc[ct][r]);
    m = fmaxf(m, __shfl_xor(m, 16));
    m = fmaxf(m, __shfl_xor(m, 32));

    if (__any(m > mrow + 8.f)) {
      float mnew = fmaxf(mrow, m);
      float alpha = EXP2F(mrow - mnew);
      mrow = mnew;
      float rs = 0.f;
#pragma unroll
      for (int ct = 0; ct < 4; ct++)
#pragma unroll
        for (int r = 0; r < 4; r++) {
          float p = EXP2F(sc[ct][r] - mnew);
          sc[ct][r] = p;
          rs += p;
        }
      lrow = lrow * alpha + rs;
#pragma unroll
      for (int ci = 0; ci < 10; ci++) oacc[ci] *= alpha;
    } else {
      float rs = 0.f;
#pragma unroll
      for (int ct = 0; ct < 4; ct++)
#pragma unroll
        for (int r = 0; r < 4; r++) {
          float p = EXP2F(sc[ct][r] - mrow);
          sc[ct][r] = p;
          rs += p;
        }
      lrow += rs;
    }

    // pack P to bf16 pairs: pk0[ct] = {r0,r1}, pk1[ct] = {r2,r3}
    unsigned pk0[4], pk1[4];
#pragma unroll
    for (int ct = 0; ct < 4; ct++) {
      pk0[ct] = cvtpk_bf16(sc[ct][0], sc[ct][1]);
      pk1[ct] = cvtpk_bf16(sc[ct][2], sc[ct][3]);
    }

    // V(t) ready (leave the 6 K(t+1) loads in flight)
    if (!last) { asm volatile("s_waitcnt vmcnt(6)" ::: "memory"); }
    else       { asm volatile("s_waitcnt vmcnt(0)" ::: "memory"); }
    fence_barrier();

    // PV: pf built via ds_bpermute (register-only, no LDS buffer)
#pragma unroll
    for (int kt2 = 0; kt2 < 2; kt2++) {
      const int cA = kt2 * 2, cB = kt2 * 2 + 1;
      int a0 = __builtin_amdgcn_ds_bpermute(addr0, (int)pk0[cA]);
      int a1 = __builtin_amdgcn_ds_bpermute(addr0, (int)pk1[cA]);
      int a2 = __builtin_amdgcn_ds_bpermute(addr1, (int)pk0[cA]);
      int a3 = __builtin_amdgcn_ds_bpermute(addr1, (int)pk1[cA]);
      int b0 = __builtin_amdgcn_ds_bpermute(addr0, (int)pk0[cB]);
      int b1 = __builtin_amdgcn_ds_bpermute(addr0, (int)pk1[cB]);
      int b2 = __builtin_amdgcn_ds_bpermute(addr1, (int)pk0[cB]);
      int b3 = __builtin_amdgcn_ds_bpermute(addr1, (int)pk1[cB]);
      u32x4 d;
      d[0] = (unsigned)(hihalf ? b0 : a0);
      d[1] = (unsigned)(hihalf ? b1 : a1);
      d[2] = (unsigned)(hihalf ? b2 : a2);
      d[3] = (unsigned)(hihalf ? b3 : a3);
      u16x8 pf = __builtin_bit_cast(u16x8, d);
#pragma unroll
      for (int ci = 0; ci < 10; ci++) {
        int c = ci * 16 + (lane & 15);
        int jl = kt2 * 4 + (lane >> 4);
        u16x8 vf = *(const u16x8*)(&Vts[c * 64 + ((jl ^ (c & 7)) << 3)]);
        oacc[ci] = mfma16(vf, pf, oacc[ci]);   // col = q, row = c
      }
    }

    fence_barrier();                    // all waves done reading Vts(t)
    if (!last) { vbase += 64; STAGE_V(); }       // V(t+1) overlaps next QK
  }
#undef STAGE_K
#undef STAGE_V

  // final l reduce across the 4 lane-groups
  lrow += __shfl_xor(lrow, 16);
  lrow += __shfl_xor(lrow, 32);
  float linv = 1.f / lrow;

  int qrow = qb * 64 + wid * 16 + (lane & 15);
  if constexpr (SPLIT > 1) {
    size_t g0 = (size_t)sp * 4096 + (size_t)b * 2048 + qrow;
#pragma unroll
    for (int ci = 0; ci < 10; ci++) {
      int col = h * 160 + ci * 16 + ((lane >> 4) << 2);
      u16x4 v = {f2b(oacc[ci][0] * linv), f2b(oacc[ci][1] * linv),
                 f2b(oacc[ci][2] * linv), f2b(oacc[ci][3] * linv)};
      *(u16x4*)(Opart + g0 * 1280 + col) = v;
    }
    if (lane < 16) {
      size_t mi = (g0 * 8 + h) * 2;
      MLbuf[mi] = mrow;
      MLbuf[mi + 1] = lrow;
    }
  } else {
#pragma unroll
    for (int ci = 0; ci < 10; ci++) {
      int col = h * 160 + ci * 16 + ((lane >> 4) << 2);
      u16x4 v = {f2b(oacc[ci][0] * linv), f2b(oacc[ci][1] * linv),
                 f2b(oacc[ci][2] * linv), f2b(oacc[ci][3] * linv)};
      *(u16x4*)(O + ((size_t)(b * 2048) + qrow) * C + col) = v;
    }
  }
}

// ---------- 4b. combine the three kv-split parts (vec8) ----------
// O = sum_p v_p*a_p*l_p / sum_p a_p*l_p, a_p = 2^(m_p - max m)
__global__ void combine_kernel(const u16* __restrict__ Opart, const float* __restrict__ MLbuf,
                               u16* __restrict__ O) {
  int idx = blockIdx.x * 256 + threadIdx.x;   // vec8 index, 655360 total
  int token = idx / 160;
  int h = (idx - token * 160) / 20;
  size_t i0 = ((size_t)token * 8 + h) * 2;
  const size_t MLP = (size_t)4096 * 16;       // floats per part
  float m0 = MLbuf[i0], l0 = MLbuf[i0 + 1];
  float m1 = MLbuf[i0 + MLP], l1 = MLbuf[i0 + MLP + 1];
  float m2 = MLbuf[i0 + 2 * MLP], l2 = MLbuf[i0 + 2 * MLP + 1];
  float m = fmaxf(fmaxf(m0, m1), m2);
  float w0 = EXP2F(m0 - m) * l0, w1 = EXP2F(m1 - m) * l1, w2 = EXP2F(m2 - m) * l2;
  float inv = 1.f / (w0 + w1 + w2);
  w0 *= inv; w1 *= inv; w2 *= inv;
  const size_t OPP = (size_t)655360;          // vec8 per part
  u16x8 a = *(const u16x8*)(Opart + (size_t)idx * 8);
  u16x8 c = *(const u16x8*)(Opart + (OPP + idx) * 8);
  u16x8 d = *(const u16x8*)(Opart + (2 * OPP + idx) * 8);
  u16x8 o;
#pragma unroll
  for (int j = 0; j < 8; j++)
    o[j] = f2b(b2f(a[j]) * w0 + b2f(c[j]) * w1 + b2f(d[j]) * w2);
  *(u16x8*)(O + (size_t)idx * 8) = o;
}

// ---------- 5. out-proj GEMM: C = A@B0 + bias + resid -> fp32 ----------
__launch_bounds__(256)
__global__ void gemm_out_kernel(const u16* __restrict__ A, const u16* __restrict__ Bt,
                                float* __restrict__ Cf, const float* __restrict__ bias,
                                const float* __restrict__ resid) {
  const int K = 1280, N = 1280;
  __shared__ u16 As[128 * 32];
  __shared__ u16 Bs[128 * 32];

  int tid = threadIdx.x;
  int wid = tid >> 6, lane = tid & 63;
  int nb = blockIdx.x, mb = blockIdx.y;
  int m0 = mb * 128, n0 = nb * 128;

  f32x4 zero = {0.f, 0.f, 0.f, 0.f};
  f32x4 acc[4][4];
#pragma unroll
  for (int i = 0; i < 4; i++)
#pragma unroll
    for (int j = 0; j < 4; j++) acc[i][j] = zero;

  int wr = wid >> 1, wc = wid & 1;

  for (int kk = 0; kk < 40; kk++) {
    int k0 = kk * 32;
#pragma unroll
    for (int i = 0; i < 2; i++) {
      int slot = i * 256 + tid;
      int row = slot >> 2, seg = slot & 3;
      async_copy16(A + (size_t)(m0 + row) * K + k0 + seg * 8, As + (size_t)(i * 256 + wid * 64) * 8);
      async_copy16(Bt + (size_t)(n0 + row) * K + k0 + seg * 8, Bs + (size_t)(i * 256 + wid * 64) * 8);
    }
    asm volatile("s_waitcnt vmcnt(0)" ::: "memory");
    __syncthreads();

    u16x8 af[4], bfr[4];
#pragma unroll
    for (int mi = 0; mi < 4; mi++)
      af[mi] = *(const u16x8*)(As + (wr * 64 + mi * 16 + (lane & 15)) * 32 + (lane >> 4) * 8);
#pragma unroll
    for (int ni = 0; ni < 4; ni++)
      bfr[ni] = *(const u16x8*)(Bs + (wc * 64 + ni * 16 + (lane & 15)) * 32 + (lane >> 4) * 8);
#pragma unroll
    for (int mi = 0; mi < 4; mi++)
#pragma unroll
      for (int ni = 0; ni < 4; ni++)
        acc[mi][ni] = mfma16(af[mi], bfr[ni], acc[mi][ni]);
    __syncthreads();
  }

#pragma unroll
  for (int mi = 0; mi < 4; mi++)
#pragma unroll
    for (int ni = 0; ni < 4; ni++)
#pragma unroll
      for (int r = 0; r < 4; r++) {
        int row = m0 + wr * 64 + mi * 16 + ((lane >> 4) << 2) + r;
        int col = n0 + wc * 64 + ni * 16 + (lane & 15);
        Cf[(size_t)row * N + col] = acc[mi][ni][r] + bias[col] + resid[(size_t)row * N + col];
      }
}

// ---------- launch ----------
extern "C" void kernel_launch(void* const* d_in, const int* in_sizes, int n_in,
                              void* d_out, int out_size, void* d_ws, size_t ws_size,
                              hipStream_t stream) {
  const float* hs      = (const float*)d_in[0];
  const float* mask    = (const float*)d_in[1];
  const float* attn_wq = (const float*)d_in[2];
  const float* attn_wk = (const float*)d_in[3];
  const float* attn_wv = (const float*)d_in[4];
  const float* out_w   = (const float*)d_in[5];
  const float* out_b   = (const float*)d_in[6];
  const float* proc_wq = (const float*)d_in[7];
  const float* proc_wk = (const float*)d_in[8];
  const float* proc_wv = (const float*)d_in[9];
  const float* ww      = (const float*)d_in[10];
  const float* wb      = (const float*)d_in[11];
  float* out = (float*)d_out;

  char* ws = (char*)d_ws;
  const size_t TOK = (size_t)4096 * 1280;     // tokens x channels
  u16* hsb = (u16*)(ws);
  u16* Qb  = (u16*)(ws + 2 * TOK);
  u16* Kb  = (u16*)(ws + 4 * TOK);
  u16* VTb = (u16*)(ws + 6 * TOK);            // V^T [16][160][2048]
  u16* AOb = (u16*)(ws + 8 * TOK);            // doubles as Qp temp before flash
  u16* Wt  = (u16*)(ws + 10 * TOK);           // 7 x 1280x1280 bf16
  float* wgate = (float*)(ws + 10 * TOK + (size_t)7 * 1280 * 1280 * 2);
  char* extra = ws + 10 * TOK + (size_t)7 * 1280 * 1280 * 2 + 16384;
  u16* Opart = (u16*)extra;                                     // [3][4096][1280] bf16
  float* MLbuf = (float*)(extra + (size_t)3 * 4096 * 1280 * 2); // [3][4096][8]{m,l}
  size_t need = (size_t)(extra - ws) + (size_t)3 * 4096 * 1280 * 2 + (size_t)3 * 4096 * 8 * 8;

  prep_kernel<<<4096, 256, 0, stream>>>(hs, mask, ww, wb, hsb, wgate);
  wtrans_kernel<<<dim3(40, 40, 7), 256, 0, stream>>>(attn_wq, attn_wk, attn_wv, out_w,
                                                     proc_wq, proc_wk, proc_wv, Wt);
  const size_t WSZ = (size_t)1280 * 1280;
  // merged Qa/Qp/K/V GEMM: 1280 uniform blocks
  gemm_qkv_kernel<<<dim3(10, 32, 4), 256, 0, stream>>>(hsb, Wt, Qb, AOb, Kb, VTb);
  // 1/sqrt(160) * log2(e): scores land in log2 domain
  const float qscale = 0.11405505533858971f;
  qblend_kernel<<<2560, 256, 0, stream>>>(Qb, AOb, wgate, qscale);

  if (ws_size >= need) {
    flash_kernel<3><<<dim3(512, 3), 256, 0, stream>>>(Qb, Kb, VTb, nullptr, Opart, MLbuf);
    combine_kernel<<<2560, 256, 0, stream>>>(Opart, MLbuf, AOb);
  } else {
    flash_kernel<1><<<dim3(512, 1), 256, 0, stream>>>(Qb, Kb, VTb, AOb, nullptr, nullptr);
  }
  gemm_out_kernel<<<dim3(10, 32), 256, 0, stream>>>(AOb, Wt + 3 * WSZ, out, out_b, hs);
}